// Round 10
// baseline (505.241 us; speedup 1.0000x reference)
//
#include <hip/hip_runtime.h>

// ---------------- problem constants ----------------
#define MUL0 64
#define MUL1 32
#define NBASIS 10
#define FCH 100
#define WNUMEL 224   // 2*MUL0 + 3*MUL1
#define MIDS 96      // MUL0 + MUL1
#define MIDV 128     // MUL0 + 2*MUL1
#define EG 4         // dst nodes per workgroup (one per wave)

// weight table offsets inside ws (floats), in d_in[7..15] order
#define OFF_W1   0        // W_fc1  10x100  (1000)
#define OFF_W2   1000     // W_fc2  100x224 (22400)
#define OFF_WSCS 23400    // W_sc_s 64x64   (4096)
#define OFF_WSCV 27496    // W_sc_v 32x32   (1024)
#define OFF_WL1S 28520    // W_l1_s 64x64   (4096)
#define OFF_WL1V 32616    // W_l1_v 32x32   (1024)
#define OFF_WL2S 33640    // W_l2_s 96x64   (6144)
#define OFF_WL2V 39784    // W_l2_v 128x32  (4096)
#define OFF_WL3  43880    // W_l3   96x1    (96)
#define OFF_WEND 43976
#define OFF_FLAG 43980    // dtype flag (int)
#define OFF_W1FRAG 44032  // bf16 frag layout, 3584 ushorts = 1792 floats
#define OFF_W2FRAG 45824  // bf16 frag layout, 28672 ushorts = 14336 floats
#define OFF_DYN  60160    // start of per-node buffers

#define W1FRAG_N (112 * 32)       // 3584
#define W2FRAG_N (4 * 224 * 32)   // 28672

typedef __attribute__((ext_vector_type(8))) short short8;
typedef __attribute__((ext_vector_type(4))) float f32x4;

// ---------------- helpers ----------------
__device__ __forceinline__ float bf2f(unsigned short h) {
    unsigned int u = ((unsigned int)h) << 16;
    float f; __builtin_memcpy(&f, &u, 4); return f;
}
__device__ __forceinline__ unsigned short f2bf(float f) {
    unsigned int u; __builtin_memcpy(&u, &f, 4);
    u += 0x7fffu + ((u >> 16) & 1u);   // round-to-nearest-even
    return (unsigned short)(u >> 16);
}
__device__ __forceinline__ float fast_silu(float x) {
    return x * __builtin_amdgcn_rcpf(1.0f + __expf(-x));
}
template<bool BF>
__device__ __forceinline__ float ldf(const void* p, size_t i) {
    if constexpr (BF) return bf2f(((const unsigned short*)p)[i]);
    else              return ((const float*)p)[i];
}
template<bool BF>
__device__ __forceinline__ void stf(void* p, size_t i, float v) {
    if constexpr (BF) ((unsigned short*)p)[i] = f2bf(v);
    else              ((float*)p)[i] = v;
}
// 4 consecutive elements starting at 4-aligned index i -> f32x4
template<bool BF>
__device__ __forceinline__ f32x4 ld4(const void* p, size_t i) {
    if constexpr (BF) {
        ushort4 h = *(const ushort4*)((const unsigned short*)p + i);
        return (f32x4){bf2f(h.x), bf2f(h.y), bf2f(h.z), bf2f(h.w)};
    } else {
        return *(const f32x4*)((const float*)p + i);
    }
}
__device__ __forceinline__ int wave_incl_scan(int v) {
    int lane = threadIdx.x & 63;
    #pragma unroll
    for (int d = 1; d < 64; d <<= 1) {
        int t = __shfl_up(v, d, 64);
        if (lane >= d) v += t;
    }
    return v;
}

// ---------------- k_prep: probe + convert + frag build + cnt zero ----------
__global__ __launch_bounds__(256) void k_prep(
    const void* __restrict__ attr,
    const void* __restrict__ a0, const void* __restrict__ a1,
    const void* __restrict__ a2, const void* __restrict__ a3,
    const void* __restrict__ a4, const void* __restrict__ a5,
    const void* __restrict__ a6, const void* __restrict__ a7,
    const void* __restrict__ a8,
    float* __restrict__ wsf,
    unsigned short* __restrict__ w1frag, unsigned short* __restrict__ w2frag,
    int* __restrict__ cnt, int* __restrict__ flag, int Nn)
{
    const bool bf = (((const unsigned int*)attr)[0] == 0x3F803F80u);
    int m = blockIdx.x * 256 + threadIdx.x;
    if (m == 0) *flag = bf ? 1 : 0;

    if (m < OFF_WEND) {
        const void* p; int off = m;
        if      (m < OFF_W2)   { p = a0; }
        else if (m < OFF_WSCS) { p = a1; off = m - OFF_W2; }
        else if (m < OFF_WSCV) { p = a2; off = m - OFF_WSCS; }
        else if (m < OFF_WL1S) { p = a3; off = m - OFF_WSCV; }
        else if (m < OFF_WL1V) { p = a4; off = m - OFF_WL1S; }
        else if (m < OFF_WL2S) { p = a5; off = m - OFF_WL1V; }
        else if (m < OFF_WL2V) { p = a6; off = m - OFF_WL2S; }
        else if (m < OFF_WL3)  { p = a7; off = m - OFF_WL2V; }
        else                   { p = a8; off = m - OFF_WL3; }
        wsf[m] = bf ? ldf<true>(p, off) : ldf<false>(p, off);
        return;
    }
    m -= OFF_WEND;
    if (m < W1FRAG_N) {
        int col = m >> 5, k = m & 31;
        float v = 0.f;
        if (col < FCH && k < NBASIS)
            v = bf ? ldf<true>(a0, k * FCH + col) : ldf<false>(a0, k * FCH + col);
        w1frag[m] = f2bf(v);
        return;
    }
    m -= W1FRAG_N;
    if (m < W2FRAG_N) {
        int q = m / (224 * 32); int r = m - q * 224 * 32;
        int n = r >> 5; int kk = r & 31;
        int k = q * 32 + kk;
        float v = 0.f;
        if (k < FCH)
            v = bf ? ldf<true>(a1, k * WNUMEL + n) : ldf<false>(a1, k * WNUMEL + n);
        w2frag[m] = f2bf(v);
        return;
    }
    m -= W2FRAG_N;
    if (m < Nn) cnt[m] = 0;
}

// ---------------- k_pre_s / k_pre_v: node precompute as LDS-weight GEMMs ---
// f_s[n][64] = (ns[n][:] @ W_l1_s) * attr[n]
// f_v[n][u][c] = (sum_k nv[n][k][c] W_l1_v[k][u]) * attr[n]
#define PS_STRIDE 68   // 272 B rows, 17 granules (odd) -> conflict-free b128
#define PV_STRIDE 36   // 144 B rows, 9 granules (odd)

template<bool BF>
__device__ __forceinline__ void pre_s_body(
    const void* __restrict__ ns, const void* __restrict__ attr,
    const float* Wt, float* __restrict__ f_s, int Nn, int lane, int nb)
{
    float acc[8]; int nidx[8];
    #pragma unroll
    for (int r = 0; r < 8; r++) {
        acc[r] = 0.f;
        int n = nb + r; nidx[r] = (n < Nn) ? n : (Nn - 1);
    }
    #pragma unroll 2
    for (int t = 0; t < 16; t++) {
        f32x4 wv = *(const f32x4*)&Wt[lane * PS_STRIDE + 4 * t];
        #pragma unroll
        for (int r = 0; r < 8; r++) {
            f32x4 x = ld4<BF>(ns, (size_t)nidx[r] * 64 + 4 * t);
            acc[r] = fmaf(x[0], wv[0], acc[r]);
            acc[r] = fmaf(x[1], wv[1], acc[r]);
            acc[r] = fmaf(x[2], wv[2], acc[r]);
            acc[r] = fmaf(x[3], wv[3], acc[r]);
        }
    }
    #pragma unroll
    for (int r = 0; r < 8; r++) {
        int n = nb + r;
        if (n < Nn) {
            float at = ldf<BF>(attr, n);
            f_s[(size_t)n * 64 + lane] = acc[r] * at;
        }
    }
}

__global__ __launch_bounds__(256) void k_pre_s(
    const void* __restrict__ ns, const void* __restrict__ attr,
    const float* __restrict__ Wl1s, float* __restrict__ f_s, int Nn)
{
    __shared__ float Wt[64 * PS_STRIDE];   // 17408 B
    const int tid = threadIdx.x;
    const bool bf = (((const unsigned int*)attr)[0] == 0x3F803F80u);
    for (int i = tid; i < 64 * 64; i += 256) {
        int u = i >> 6, j = i & 63;
        Wt[j * PS_STRIDE + u] = Wl1s[u * 64 + j];
    }
    __syncthreads();
    const int lane = tid & 63;
    const int wave = __builtin_amdgcn_readfirstlane(tid >> 6);
    const int nb   = (blockIdx.x * 4 + wave) * 8;
    if (nb >= Nn) return;
    if (bf) pre_s_body<true >(ns, attr, Wt, f_s, Nn, lane, nb);
    else    pre_s_body<false>(ns, attr, Wt, f_s, Nn, lane, nb);
}

template<bool BF>
__device__ __forceinline__ void pre_v_body(
    const void* __restrict__ nv, const void* __restrict__ attr,
    const float* Wt, float* __restrict__ f_v, int Nn, int lane, int ub)
{
    const int vi  = lane & 31;
    const int grp = lane >> 5;
    const int NU  = 3 * Nn;
    float acc[8]; int nn_[8], cc_[8];
    #pragma unroll
    for (int r = 0; r < 8; r++) {
        acc[r] = 0.f;
        int g = ub + grp * 8 + r;
        if (g > NU - 1) g = NU - 1;
        nn_[r] = (int)((unsigned)g / 3u);
        cc_[r] = g - 3 * nn_[r];
    }
    #pragma unroll 2
    for (int t = 0; t < 8; t++) {
        f32x4 wv = *(const f32x4*)&Wt[vi * PV_STRIDE + 4 * t];
        #pragma unroll
        for (int r = 0; r < 8; r++) {
            size_t b = (size_t)nn_[r] * 96 + (size_t)(4 * t) * 3 + cc_[r];
            float x0 = ldf<BF>(nv, b);
            float x1 = ldf<BF>(nv, b + 3);
            float x2 = ldf<BF>(nv, b + 6);
            float x3 = ldf<BF>(nv, b + 9);
            acc[r] = fmaf(x0, wv[0], acc[r]);
            acc[r] = fmaf(x1, wv[1], acc[r]);
            acc[r] = fmaf(x2, wv[2], acc[r]);
            acc[r] = fmaf(x3, wv[3], acc[r]);
        }
    }
    #pragma unroll
    for (int r = 0; r < 8; r++) {
        int g = ub + grp * 8 + r;
        if (g < NU) {
            int n = nn_[r], c = cc_[r];
            float at = ldf<BF>(attr, n);
            f_v[(size_t)n * 96 + vi * 3 + c] = acc[r] * at;
        }
    }
}

__global__ __launch_bounds__(256) void k_pre_v(
    const void* __restrict__ nv, const void* __restrict__ attr,
    const float* __restrict__ Wl1v, float* __restrict__ f_v, int Nn)
{
    __shared__ float Wt[32 * PV_STRIDE];   // 4608 B
    const int tid = threadIdx.x;
    const bool bf = (((const unsigned int*)attr)[0] == 0x3F803F80u);
    for (int i = tid; i < 32 * 32; i += 256) {
        int u = i >> 5, vi = i & 31;
        Wt[vi * PV_STRIDE + u] = Wl1v[u * 32 + vi];
    }
    __syncthreads();
    const int lane = tid & 63;
    const int wave = __builtin_amdgcn_readfirstlane(tid >> 6);
    const int ub   = (blockIdx.x * 4 + wave) * 16;
    if (ub >= 3 * Nn) return;
    if (bf) pre_v_body<true >(nv, attr, Wt, f_v, Nn, lane, ub);
    else    pre_v_body<false>(nv, attr, Wt, f_v, Nn, lane, ub);
}

// ---------------- CSR: histogram ----------------
__global__ __launch_bounds__(256) void k_hist(
    const int* __restrict__ edst, int* __restrict__ cnt, int Ecnt)
{
    int e = blockIdx.x * 256 + threadIdx.x;
    if (e < Ecnt) atomicAdd(&cnt[edst[e]], 1);
}

// ---------------- 3-phase parallel scan ----------
__global__ __launch_bounds__(256) void k_scan_blk(
    const int* __restrict__ cnt, int* __restrict__ row_part,
    int* __restrict__ blk_sum, int Nn)
{
    __shared__ int ws4[4];
    int tid = threadIdx.x, lane = tid & 63, wid = tid >> 6;
    int i = blockIdx.x * 256 + tid;
    int v = (i < Nn) ? cnt[i] : 0;
    int incl = wave_incl_scan(v);
    if (lane == 63) ws4[wid] = incl;
    __syncthreads();
    int off = 0;
    #pragma unroll
    for (int w2 = 0; w2 < 4; w2++) off += (w2 < wid) ? ws4[w2] : 0;
    if (i < Nn) row_part[i] = off + incl - v;
    if (tid == 0) blk_sum[blockIdx.x] = ws4[0] + ws4[1] + ws4[2] + ws4[3];
}

__global__ __launch_bounds__(256) void k_scan_top(
    const int* __restrict__ blk_sum, int* __restrict__ blk_off,
    int* __restrict__ row_start, int NB, int Nn)
{
    __shared__ int ws4[4];
    int tid = threadIdx.x, lane = tid & 63, wid = tid >> 6;
    int v = (tid < NB) ? blk_sum[tid] : 0;
    int incl = wave_incl_scan(v);
    if (lane == 63) ws4[wid] = incl;
    __syncthreads();
    int off = 0;
    #pragma unroll
    for (int w2 = 0; w2 < 4; w2++) off += (w2 < wid) ? ws4[w2] : 0;
    if (tid < NB) blk_off[tid] = off + incl - v;
    if (tid == 0) row_start[Nn] = ws4[0] + ws4[1] + ws4[2] + ws4[3];
}

__global__ __launch_bounds__(256) void k_rowfix(
    const int* __restrict__ row_part, const int* __restrict__ blk_off,
    int* __restrict__ row_start, int* __restrict__ cur, int Nn)
{
    int i = blockIdx.x * 256 + threadIdx.x;
    if (i < Nn) { row_start[i] = blk_off[i >> 8] + row_part[i]; cur[i] = 0; }
}

// ---------------- fallback single-wg scan (old path) ----------------
__global__ __launch_bounds__(1024) void k_scan1(
    const int* __restrict__ cnt, int* __restrict__ row_start,
    int* __restrict__ cur, int Nn)
{
    __shared__ int wsum[16];
    __shared__ int s_off, s_tot;
    int tid = threadIdx.x, lane = tid & 63, wid = tid >> 6;
    if (tid == 0) s_off = 0;
    __syncthreads();
    for (int base = 0; base < Nn; base += 1024) {
        int i = base + tid;
        int v = (i < Nn) ? cnt[i] : 0;
        int incl = wave_incl_scan(v);
        if (lane == 63) wsum[wid] = incl;
        __syncthreads();
        if (wid == 0) {
            int wv = (lane < 16) ? wsum[lane] : 0;
            int wincl = wave_incl_scan(wv);
            if (lane < 16) wsum[lane] = wincl - wv;
            if (lane == 15) s_tot = wincl;
        }
        __syncthreads();
        int excl = s_off + wsum[wid] + incl - v;
        if (i < Nn) { row_start[i] = excl; cur[i] = 0; }
        __syncthreads();
        if (tid == 0) s_off += s_tot;
        __syncthreads();
    }
    if (threadIdx.x == 0) row_start[Nn] = s_off;
}

// ---------------- k_place ----------------
__global__ __launch_bounds__(256) void k_place(
    const int* __restrict__ edst, const int* __restrict__ esrc,
    const void* __restrict__ eattr,
    const int* __restrict__ row_start, int* __restrict__ cur,
    int* __restrict__ perm, int* __restrict__ srcs, float* __restrict__ y4,
    int Ecnt, const int* __restrict__ flag, int extras)
{
    int e = blockIdx.x * 256 + threadIdx.x;
    if (e >= Ecnt) return;
    int d = edst[e];
    int pos = row_start[d] + atomicAdd(&cur[d], 1);
    perm[pos] = e;
    if (extras) {
        srcs[pos] = esrc[e];
        float4 yv;
        if (*flag) {
            const unsigned short* ap = (const unsigned short*)eattr + (size_t)e * 4;
            yv = make_float4(bf2f(ap[0]), bf2f(ap[1]), bf2f(ap[2]), bf2f(ap[3]));
        } else {
            const float* ap = (const float*)eattr + (size_t)e * 4;
            yv = make_float4(ap[0], ap[1], ap[2], ap[3]);
        }
        ((float4*)y4)[pos] = yv;
    }
}

// ---------------- k_fc: dense per-edge MLP (MFMA), edge-major wbuf ---------
// 128-EDGE TILE: FC1 runs twice per wave (groups wave, wave+4); FC2 is
// COLUMN-SPLIT across waves and each B-fragment is reused across 8 edge
// groups (2x less w2frag L2 traffic per edge than the 64-edge tile, plus
// half the barriers/launch overhead per edge).
#define HFC_STRIDE 136   // 272 B rows, 16B-aligned

__global__ __launch_bounds__(256) void k_fc(
    const void* __restrict__ escal, const int* __restrict__ perm,
    const unsigned short* __restrict__ w1frag, const unsigned short* __restrict__ w2frag,
    unsigned short* __restrict__ wbuf, int Ecnt, const int* __restrict__ flag)
{
    __shared__ __align__(16) unsigned short h_lds[128 * HFC_STRIDE]; // 34.8 KB
    const int tid  = threadIdx.x;
    const int lane = tid & 63;
    const int wave = tid >> 6;
    const int nl   = lane & 15;
    const int quad = lane >> 4;
    const int tb   = blockIdx.x * 128;

    // zero h padding cols 112..127 (128 rows)
    for (int i = tid; i < 128 * 16; i += 256) {
        int row = i >> 4;
        h_lds[row * HFC_STRIDE + 112 + (i & 15)] = 0;
    }

    // FC1 for two 16-edge groups per wave: g = wave, wave+4
    #pragma unroll
    for (int gi = 0; gi < 2; gi++) {
        const int g = wave + gi * 4;
        int eidx = tb + 16 * g + nl;
        if (eidx >= Ecnt) eidx = Ecnt - 1;
        const int e = perm[eidx];
        short8 a = {0, 0, 0, 0, 0, 0, 0, 0};
        if (*flag) {
            const unsigned int* p = (const unsigned int*)((const unsigned short*)escal + (size_t)e * NBASIS);
            if (quad == 0) {
                unsigned int d0 = p[0], d1 = p[1], d2 = p[2], d3 = p[3];
                a = (short8){(short)d0, (short)(d0 >> 16), (short)d1, (short)(d1 >> 16),
                             (short)d2, (short)(d2 >> 16), (short)d3, (short)(d3 >> 16)};
            } else if (quad == 1) {
                unsigned int d4 = p[4];
                a = (short8){(short)d4, (short)(d4 >> 16), 0, 0, 0, 0, 0, 0};
            }
        } else {
            const float* p = (const float*)escal + (size_t)e * NBASIS;
            if (quad == 0) {
                a = (short8){(short)f2bf(p[0]), (short)f2bf(p[1]), (short)f2bf(p[2]), (short)f2bf(p[3]),
                             (short)f2bf(p[4]), (short)f2bf(p[5]), (short)f2bf(p[6]), (short)f2bf(p[7])};
            } else if (quad == 1) {
                a = (short8){(short)f2bf(p[8]), (short)f2bf(p[9]), 0, 0, 0, 0, 0, 0};
            }
        }

        f32x4 hacc[7];
        #pragma unroll
        for (int t = 0; t < 7; t++) {
            short8 b = *(const short8*)&w1frag[(16 * t + nl) * 32 + quad * 8];
            hacc[t] = __builtin_amdgcn_mfma_f32_16x16x32_bf16(
                a, b, (f32x4){0.f, 0.f, 0.f, 0.f}, 0, 0, 0);
        }
        #pragma unroll
        for (int t = 0; t < 7; t++) {
            #pragma unroll
            for (int r = 0; r < 4; r++)
                h_lds[(16 * g + quad * 4 + r) * HFC_STRIDE + 16 * t + nl] =
                    f2bf(fast_silu(hacc[t][r]));
        }
    }
    __syncthreads();

    // FC2 column-split: wave owns t-tiles; B-fragments reused across 8
    // edge-groups. tsta/tend: waves 0,1 -> 4 tiles; waves 2,3 -> 3 tiles.
    {
        const int tsta = (wave < 2) ? wave * 4 : 8 + (wave - 2) * 3;
        const int tend = (wave < 2) ? tsta + 4 : tsta + 3;
        for (int t = tsta; t < tend; t++) {
            short8 b0 = *(const short8*)&w2frag[(0 * 224 + 16 * t + nl) * 32 + quad * 8];
            short8 b1 = *(const short8*)&w2frag[(1 * 224 + 16 * t + nl) * 32 + quad * 8];
            short8 b2 = *(const short8*)&w2frag[(2 * 224 + 16 * t + nl) * 32 + quad * 8];
            short8 b3 = *(const short8*)&w2frag[(3 * 224 + 16 * t + nl) * 32 + quad * 8];
            #pragma unroll 2
            for (int eg = 0; eg < 8; eg++) {
                const unsigned short* hrow = &h_lds[(16 * eg + nl) * HFC_STRIDE];
                f32x4 c = {0.f, 0.f, 0.f, 0.f};
                c = __builtin_amdgcn_mfma_f32_16x16x32_bf16(
                    *(const short8*)&hrow[0 * 32 + quad * 8], b0, c, 0, 0, 0);
                c = __builtin_amdgcn_mfma_f32_16x16x32_bf16(
                    *(const short8*)&hrow[1 * 32 + quad * 8], b1, c, 0, 0, 0);
                c = __builtin_amdgcn_mfma_f32_16x16x32_bf16(
                    *(const short8*)&hrow[2 * 32 + quad * 8], b2, c, 0, 0, 0);
                c = __builtin_amdgcn_mfma_f32_16x16x32_bf16(
                    *(const short8*)&hrow[3 * 32 + quad * 8], b3, c, 0, 0, 0);
                #pragma unroll
                for (int r = 0; r < 4; r++)
                    wbuf[(size_t)(tb + 16 * eg + quad * 4 + r) * WNUMEL + 16 * t + nl] =
                        f2bf(c[r]);
            }
        }
    }
}

// ---------------- k_agg: one wave per dst; FOUR chains, zero shuffles ------
// agg_s[n][96] coalesced; agg_v stored C-MAJOR: aggv[n*384 + c*128 + u]
// Quarter-split chains, branch-free: invalid indices clamp to dhi-1 and the
// y-vector is zeroed, nullifying every accumulation term (all terms carry a
// y factor on their live path).
__global__ __launch_bounds__(256) void k_agg(
    const unsigned short* __restrict__ wbuf,
    const int* __restrict__ srcs, const float* __restrict__ y4,
    const int* __restrict__ row_start,
    const float* __restrict__ f_s, const float* __restrict__ f_v,
    const float* __restrict__ Wl3, const void* __restrict__ attr,
    float* __restrict__ agg_s, float* __restrict__ aggv,
    float* __restrict__ cosb, float* __restrict__ sinb,
    int Nn, const int* __restrict__ flag)
{
    const int tid  = threadIdx.x;
    const int lane = tid & 63;
    const int wave = tid >> 6;
    const int node = blockIdx.x * EG + wave;
    if (node >= Nn) return;

    const int lane2 = lane & 31;
    const bool hi = (lane >= 32);

    const int dlo = row_start[node];
    const int dhi = row_start[node + 1];
    const int deg = dhi - dlo;
    const int q   = (deg + 3) >> 2;

    const float k14 = 0.25f;
    const float k13 = 0.25f * 0.57735026918962576451f;
    const float k12 = 0.25f * 0.70710678118654752440f;

    float A0[4], A1[4], S0[4], S1[4], S2[4], V0[4], V1[4], V2[4];
    #pragma unroll
    for (int c = 0; c < 4; c++) {
        A0[c] = A1[c] = S0[c] = S1[c] = S2[c] = V0[c] = V1[c] = V2[c] = 0.f;
    }

    for (int j = 0; j < q; j++) {
        #pragma unroll
        for (int c = 0; c < 4; c++) {
            const int idxr = dlo + c * q + j;
            const int idx_ = (idxr < dhi) ? idxr : (dhi - 1);
            const float vm = (idxr < dhi) ? 1.f : 0.f;
            const int srcn = srcs[idx_];
            const float4 y = ((const float4*)y4)[idx_];
            const float y0 = y.x * vm, y1x = y.y * vm, y1y = y.z * vm, y1z = y.w * vm;
            const unsigned short* wrow = wbuf + (size_t)idx_ * WNUMEL;
            const float* fsr = f_s + (size_t)srcn * 64;
            const float* fvr = f_v + (size_t)srcn * 96;
            float fs_l = fsr[lane];
            float v0 = fvr[lane2 * 3 + 0];
            float v1 = fvr[lane2 * 3 + 1];
            float v2 = fvr[lane2 * 3 + 2];
            float w00 = bf2f(wrow[lane]);
            float w01 = bf2f(wrow[64 + lane]);
            float wh  = bf2f(wrow[128 + lane]);
            float wx  = bf2f(wrow[160 + lane]);

            A0[c] = fmaf(w00 * fs_l, y0 * k14, A0[c]);
            float dot_ = v0 * y1x + v1 * y1y + v2 * y1z;
            A1[c] = fmaf(wh * dot_, k13, A1[c]);
            float t1_ = w01 * fs_l * k14;
            S0[c] = fmaf(t1_, y1x, S0[c]);
            S1[c] = fmaf(t1_, y1y, S1[c]);
            S2[c] = fmaf(t1_, y1z, S2[c]);
            float cx_ = v1 * y1z - v2 * y1y;
            float cy_ = v2 * y1x - v0 * y1z;
            float cz_ = v0 * y1y - v1 * y1x;
            float e0_ = hi ? cx_ : v0;
            float e1_ = hi ? cy_ : v1;
            float e2_ = hi ? cz_ : v2;
            float tv_ = hi ? (wx * k12) : (wh * (y0 * k14));
            V0[c] = fmaf(e0_, tv_, V0[c]);
            V1[c] = fmaf(e1_, tv_, V1[c]);
            V2[c] = fmaf(e2_, tv_, V2[c]);
        }
    }

    const float acc0  = (A0[0] + A0[1]) + (A0[2] + A0[3]);
    const float acc1  = (A1[0] + A1[1]) + (A1[2] + A1[3]);
    const float accS0 = (S0[0] + S0[1]) + (S0[2] + S0[3]);
    const float accS1 = (S1[0] + S1[1]) + (S1[2] + S1[3]);
    const float accS2 = (S2[0] + S2[1]) + (S2[2] + S2[3]);
    const float accV0 = (V0[0] + V0[1]) + (V0[2] + V0[3]);
    const float accV1 = (V1[0] + V1[1]) + (V1[2] + V1[3]);
    const float accV2 = (V2[0] + V2[1]) + (V2[2] + V2[3]);

    // writeback: agg_s coalesced; aggv c-major; angle -> cos/sin
    {
        float* as = agg_s + (size_t)node * MIDS;
        float* av = aggv  + (size_t)node * 384;
        as[lane] = acc0;
        if (hi) as[64 + lane2] = acc1;

        av[0 * 128 + lane] = accS0;
        av[1 * 128 + lane] = accS1;
        av[2 * 128 + lane] = accS2;
        const int vrow = hi ? (96 + lane2) : (64 + lane);
        av[0 * 128 + vrow] = accV0;
        av[1 * 128 + vrow] = accV1;
        av[2 * 128 + vrow] = accV2;

        float avv = acc0 * Wl3[lane];
        if (hi) avv = fmaf(acc1, Wl3[64 + lane2], avv);
        #pragma unroll
        for (int d = 1; d < 64; d <<= 1) avv += __shfl_xor(avv, d);
        if (lane == 0) {
            float at = (*flag) ? ldf<true>(attr, node) : ldf<false>(attr, node);
            float aa = 0.1f * avv * at;
            cosb[node] = __cosf(aa);
            sinb[node] = __sinf(aa);
        }
    }
}

// ---------------- k_final_s / k_final_v: LDS-weight register-blocked GEMMs -
// Wt row stride 164 floats = 656 B = 41 (odd) 16B-granules -> within any
// 16-lane phase the granule index == 41*lane mod 8 covers all 8 slots twice
// -> <=2-way LDS access on ds_read_b128 (free, m136).
#define WT_STRIDE 164

template<bool BF>
__device__ __forceinline__ void final_s_body(
    const float* __restrict__ agg_s, const void* __restrict__ ns,
    const float* __restrict__ cosb, const float* __restrict__ sinb,
    const void* __restrict__ attr, void* __restrict__ out,
    int Nn, const float* Wt, int lane, int nb)
{
    float acc_sc[8], acc_l2[8];
    int nidx[8];
    #pragma unroll
    for (int r = 0; r < 8; r++) {
        acc_sc[r] = 0.f; acc_l2[r] = 0.f;
        int n = nb + r; nidx[r] = (n < Nn) ? n : (Nn - 1);
    }
    // sc part: u = 0..63 from ns
    #pragma unroll 2
    for (int t = 0; t < 16; t++) {
        f32x4 wv = *(const f32x4*)&Wt[lane * WT_STRIDE + 4 * t];
        #pragma unroll
        for (int r = 0; r < 8; r++) {
            f32x4 x = ld4<BF>(ns, (size_t)nidx[r] * 64 + 4 * t);
            acc_sc[r] = fmaf(x[0], wv[0], acc_sc[r]);
            acc_sc[r] = fmaf(x[1], wv[1], acc_sc[r]);
            acc_sc[r] = fmaf(x[2], wv[2], acc_sc[r]);
            acc_sc[r] = fmaf(x[3], wv[3], acc_sc[r]);
        }
    }
    // l2 part: u = 0..95 from agg_s
    #pragma unroll 2
    for (int t = 0; t < 24; t++) {
        f32x4 wv = *(const f32x4*)&Wt[lane * WT_STRIDE + 64 + 4 * t];
        #pragma unroll
        for (int r = 0; r < 8; r++) {
            f32x4 x = *(const f32x4*)(agg_s + (size_t)nidx[r] * 96 + 4 * t);
            acc_l2[r] = fmaf(x[0], wv[0], acc_l2[r]);
            acc_l2[r] = fmaf(x[1], wv[1], acc_l2[r]);
            acc_l2[r] = fmaf(x[2], wv[2], acc_l2[r]);
            acc_l2[r] = fmaf(x[3], wv[3], acc_l2[r]);
        }
    }
    #pragma unroll
    for (int r = 0; r < 8; r++) {
        int n = nb + r;
        if (n < Nn) {
            float cv = cosb[n], sv = sinb[n];
            float at = ldf<BF>(attr, n);
            stf<BF>(out, (size_t)n * 160 + lane, at * (cv * acc_sc[r] + sv * acc_l2[r]));
        }
    }
}

__global__ __launch_bounds__(256) void k_final_s(
    const float* __restrict__ agg_s, const void* __restrict__ ns,
    const float* __restrict__ Wscs, const float* __restrict__ Wl2s,
    const float* __restrict__ cosb, const float* __restrict__ sinb,
    const void* __restrict__ attr, void* __restrict__ out,
    int Nn, const int* __restrict__ flag)
{
    __shared__ float Wt[64 * WT_STRIDE];   // 41984 B
    const int tid = threadIdx.x;
    // Wt[j][u]: u<64 -> Wscs[u][j]; u>=64 -> Wl2s[u-64][j]
    for (int i = tid; i < 160 * 64; i += 256) {
        int u = i >> 6, j = i & 63;
        float w = (u < 64) ? Wscs[u * 64 + j] : Wl2s[(u - 64) * 64 + j];
        Wt[j * WT_STRIDE + u] = w;
    }
    __syncthreads();

    const int lane = tid & 63;
    const int wave = __builtin_amdgcn_readfirstlane(tid >> 6);
    const int nb   = (blockIdx.x * 4 + wave) * 8;
    if (nb >= Nn) return;
    if (*flag) final_s_body<true >(agg_s, ns, cosb, sinb, attr, out, Nn, Wt, lane, nb);
    else       final_s_body<false>(agg_s, ns, cosb, sinb, attr, out, Nn, Wt, lane, nb);
}

template<bool BF>
__device__ __forceinline__ void final_v_body(
    const float* __restrict__ aggv, const void* __restrict__ nv,
    const float* __restrict__ cosb, const float* __restrict__ sinb,
    const void* __restrict__ attr, void* __restrict__ out,
    int Nn, const float* Wt, int lane, int ub)
{
    const int vi   = lane & 31;
    const int grp  = lane >> 5;       // two row-groups share Wt addresses
    const int NU   = 3 * Nn;
    float acc_sc[8], acc_l2[8];
    int gidx[8], nn_[8], cc_[8];
    #pragma unroll
    for (int r = 0; r < 8; r++) {
        acc_sc[r] = 0.f; acc_l2[r] = 0.f;
        int g = ub + grp * 8 + r;
        if (g > NU - 1) g = NU - 1;
        gidx[r] = g;
        nn_[r] = (int)((unsigned)g / 3u);
        cc_[r] = g - 3 * nn_[r];
    }
    // sc part: u = 0..31 from nv[n][u][c] (stride 3)
    #pragma unroll 2
    for (int t = 0; t < 8; t++) {
        f32x4 wv = *(const f32x4*)&Wt[vi * WT_STRIDE + 4 * t];
        #pragma unroll
        for (int r = 0; r < 8; r++) {
            size_t b = (size_t)nn_[r] * 96 + (size_t)(4 * t) * 3 + cc_[r];
            float x0 = ldf<BF>(nv, b);
            float x1 = ldf<BF>(nv, b + 3);
            float x2 = ldf<BF>(nv, b + 6);
            float x3 = ldf<BF>(nv, b + 9);
            acc_sc[r] = fmaf(x0, wv[0], acc_sc[r]);
            acc_sc[r] = fmaf(x1, wv[1], acc_sc[r]);
            acc_sc[r] = fmaf(x2, wv[2], acc_sc[r]);
            acc_sc[r] = fmaf(x3, wv[3], acc_sc[r]);
        }
    }
    // l2 part: u = 0..127 from c-major aggv rows (contiguous)
    #pragma unroll 2
    for (int t = 0; t < 32; t++) {
        f32x4 wv = *(const f32x4*)&Wt[vi * WT_STRIDE + 32 + 4 * t];
        #pragma unroll
        for (int r = 0; r < 8; r++) {
            f32x4 x = *(const f32x4*)(aggv + (size_t)gidx[r] * 128 + 4 * t);
            acc_l2[r] = fmaf(x[0], wv[0], acc_l2[r]);
            acc_l2[r] = fmaf(x[1], wv[1], acc_l2[r]);
            acc_l2[r] = fmaf(x[2], wv[2], acc_l2[r]);
            acc_l2[r] = fmaf(x[3], wv[3], acc_l2[r]);
        }
    }
    #pragma unroll
    for (int r = 0; r < 8; r++) {
        int g = ub + grp * 8 + r;
        if (g < NU) {
            int n = nn_[r], c = cc_[r];
            float cv = cosb[n], sv = sinb[n];
            float at = ldf<BF>(attr, n);
            stf<BF>(out, (size_t)n * 160 + 64 + vi * 3 + c,
                    at * (cv * acc_sc[r] + sv * acc_l2[r]));
        }
    }
}

__global__ __launch_bounds__(256) void k_final_v(
    const float* __restrict__ aggv, const void* __restrict__ nv,
    const float* __restrict__ Wscv, const float* __restrict__ Wl2v,
    const float* __restrict__ cosb, const float* __restrict__ sinb,
    const void* __restrict__ attr, void* __restrict__ out,
    int Nn, const int* __restrict__ flag)
{
    __shared__ float Wt[32 * WT_STRIDE];   // 20992 B
    const int tid = threadIdx.x;
    // Wt[j][u]: u<32 -> Wscv[u][j]; u>=32 -> Wl2v[u-32][j]
    for (int i = tid; i < 160 * 32; i += 256) {
        int u = i >> 5, j = i & 31;
        float w = (u < 32) ? Wscv[u * 32 + j] : Wl2v[(u - 32) * 32 + j];
        Wt[j * WT_STRIDE + u] = w;
    }
    __syncthreads();

    const int lane = tid & 63;
    const int wave = __builtin_amdgcn_readfirstlane(tid >> 6);
    const int ub   = (blockIdx.x * 4 + wave) * 16;
    if (ub >= 3 * Nn) return;
    if (*flag) final_v_body<true >(aggv, nv, cosb, sinb, attr, out, Nn, Wt, lane, ub);
    else       final_v_body<false>(aggv, nv, cosb, sinb, attr, out, Nn, Wt, lane, ub);
}

// ---------------- fallback fused edge kernel (round-8, verbatim) -----------
#define ES_STRIDE 40
#define H_STRIDE 136
#define WL_STRIDE 225

__global__ __launch_bounds__(256) void k_edge_mfma(
    const void* __restrict__ escal, const void* __restrict__ eattr,
    const void* __restrict__ attr,
    const int* __restrict__ esrc,
    const int* __restrict__ row_start, const int* __restrict__ perm,
    const unsigned short* __restrict__ w1frag, const unsigned short* __restrict__ w2frag,
    const float* __restrict__ Wl3,
    const float* __restrict__ f_s, const float* __restrict__ f_v,
    float* __restrict__ agg_s, float* __restrict__ agg_v,
    float* __restrict__ cosb, float* __restrict__ sinb,
    int Nn, const int* __restrict__ flag)
{
    __shared__ __align__(16) unsigned short es_lds[64 * ES_STRIDE];
    __shared__ __align__(16) unsigned short h_lds[64 * H_STRIDE];
    __shared__ __align__(16) unsigned short w_lds[64 * WL_STRIDE];
    __shared__ float y_lds[64][4];
    __shared__ int   src_lds[64];

    const int tid  = threadIdx.x;
    const int lane = tid & 63;
    const int wave = tid >> 6;
    const int nl   = lane & 15;
    const int quad = lane >> 4;
    const int gbase = blockIdx.x * EG;
    const bool isbf = (*flag != 0);

    for (int i = tid; i < 64 * 22; i += 256) {
        int row = i / 22, k = 10 + (i - row * 22);
        es_lds[row * ES_STRIDE + k] = 0;
    }
    for (int i = tid; i < 64 * 16; i += 256) {
        int row = i >> 4, k = 112 + (i & 15);
        h_lds[row * H_STRIDE + k] = 0;
    }

    const int lane2 = lane & 31;
    const int u0 = lane / 3,  c0 = lane - 3 * u0;
    const int pB = 64 + lane;
    const int uB = pB / 3,    cB = pB - 3 * uB;
    const int p2 = 128 + lane;
    const int u2 = p2 / 3,    c2 = p2 - 3 * u2;
    const int pH = 64 + lane2;
    const int uH = pH / 3,    cH = pH - 3 * uH;
    const bool half = (lane < 32);

    const int node = gbase + wave;
    const int dlo = (node < Nn) ? row_start[node] : 0;
    const int dhi = (node < Nn) ? row_start[node + 1] : 0;

    float acc[9];
    #pragma unroll
    for (int s = 0; s < 9; s++) acc[s] = 0.f;

    const int gend    = (gbase + EG < Nn) ? (gbase + EG) : Nn;
    const int e_start = row_start[gbase];
    const int e_end   = row_start[gend];

    for (int tb = e_start; tb < e_end; tb += 64) {
        const int tcnt = (e_end - tb < 64) ? (e_end - tb) : 64;
        __syncthreads();

        {
            int i = tid & 63, part = tid >> 6;
            if (i < tcnt && part < 2) {
                int e = perm[tb + i];
                if (part == 0) {
                    unsigned int* dstp = (unsigned int*)&es_lds[i * ES_STRIDE];
                    if (isbf) {
                        const unsigned int* srcp =
                            (const unsigned int*)((const unsigned short*)escal + (size_t)e * NBASIS);
                        #pragma unroll
                        for (int t2 = 0; t2 < 5; t2++) dstp[t2] = srcp[t2];
                    } else {
                        const float* srcp = (const float*)escal + (size_t)e * NBASIS;
                        #pragma unroll
                        for (int t2 = 0; t2 < 5; t2++) {
                            unsigned int lo = f2bf(srcp[2 * t2]);
                            unsigned int hi = f2bf(srcp[2 * t2 + 1]);
                            dstp[t2] = lo | (hi << 16);
                        }
                    }
                } else {
                    src_lds[i] = esrc[e];
                    if (isbf) {
                        const unsigned short* ap = (const unsigned short*)eattr + (size_t)e * 4;
                        #pragma unroll
                        for (int t2 = 0; t2 < 4; t2++) y_lds[i][t2] = bf2f(ap[t2]);
                    } else {
                        const float* ap = (const float*)eattr + (size_t)e * 4;
                        #pragma unroll
                        for (int t2 = 0; t2 < 4; t2++) y_lds[i][t2] = ap[t2];
                    }
                }
            }
        }
        __syncthreads();

        {
            short8 a = *(const short8*)&es_lds[(16 * wave + nl) * ES_STRIDE + quad * 8];
            f32x4 hacc[7];
            #pragma unroll
            for (int t = 0; t < 7; t++) {
                short8 b = *(const short8*)&w1frag[(16 * t + nl) * 32 + quad * 8];
                hacc[t] = __builtin_amdgcn_mfma_f32_16x16x32_bf16(
                    a, b, (f32x4){0.f, 0.f, 0.f, 0.f}, 0, 0, 0);
            }
            #pragma unroll
            for (int t = 0; t < 7; t++) {
                #pragma unroll
                for (int r = 0; r < 4; r++)
                    h_lds[(16 * wave + quad * 4 + r) * H_STRIDE + 16 * t + nl] =
                        f2bf(fast_silu(hacc[t][r]));
            }
        }
        __syncthreads();

        #pragma unroll 2
        for (int t = 0; t < 14; t++) {
            f32x4 c = {0.f, 0.f, 0.f, 0.f};
            #pragma unroll
            for (int q = 0; q < 4; q++) {
                short8 a = *(const short8*)&h_lds[(16 * wave + nl) * H_STRIDE + q * 32 + quad * 8];
                short8 b = *(const short8*)&w2frag[((q * 224) + 16 * t + nl) * 32 + quad * 8];
                c = __builtin_amdgcn_mfma_f32_16x16x32_bf16(a, b, c, 0, 0, 0);
            }
            #pragma unroll
            for (int r = 0; r < 4; r++)
                w_lds[(16 * wave + quad * 4 + r) * WL_STRIDE + 16 * t + nl] = f2bf(c[r]);
        }
        __syncthreads();

        {
            int lo = dlo > tb ? dlo : tb;
            int hi = dhi < tb + tcnt ? dhi : tb + tcnt;
            for (int idx = lo; idx < hi; idx++) {
                const int i = idx - tb;
                const int srcn = src_lds[i];
                const float y0  = y_lds[i][0];
                const float y1x = y_lds[i][1];
                const float y1y = y_lds[i][2];
                const float y1z = y_lds[i][3];
                const float* fsr = f_s + (size_t)srcn * 64;
                const float* fvr = f_v + (size_t)srcn * 96;
                const unsigned short* wrow = &w_lds[i * WL_STRIDE];

                float fs_l  = fsr[lane];
                float fs_u0 = fsr[u0];
                float fs_uB = fsr[uB];
                float fs_u2 = fsr[u2];
                float fvA0 = fvr[lane2 * 3], fvA1 = fvr[lane2 * 3 + 1], fvA2 = fvr[lane2 * 3 + 2];
                float fvB0 = fvr[u0 * 3],    fvB1 = fvr[u0 * 3 + 1],    fvB2 = fvr[u0 * 3 + 2];
                float fvH0 = fvr[uH * 3],    fvH1 = fvr[uH * 3 + 1],    fvH2 = fvr[uH * 3 + 2];

                float y1c0 = (c0 == 0) ? y1x : (c0 == 1) ? y1y : y1z;
                float y1cB = (cB == 0) ? y1x : (cB == 1) ? y1y : y1z;
                float y1c2 = (c2 == 0) ? y1x : (c2 == 1) ? y1y : y1z;

                float w_s0 = bf2f(wrow[lane]);
                float w_s1 = bf2f(wrow[160 + lane2]);
                float w_s2 = bf2f(wrow[64 + u0]);
                float w_s3 = bf2f(wrow[64 + uB]);
                float w_s4 = bf2f(wrow[64 + u2]);
                float w_s5 = bf2f(wrow[128 + u0]);
                float w_s6 = bf2f(wrow[128 + uH]);
                float w_s7 = bf2f(wrow[192 + u0]);
                float w_s8 = bf2f(wrow[192 + uH]);

                const float k14 = 0.25f;
                const float k13 = 0.25f * 0.57735026918962576451f;
                const float k12 = 0.25f * 0.70710678118654752440f;

                acc[0] = fmaf(w_s0 * fs_l, y0 * k14, acc[0]);
                {
                    float dot = fvA0 * y1x + fvA1 * y1y + fvA2 * y1z;
                    acc[1] = fmaf(w_s1 * dot, k13, acc[1]);
                }
                acc[2] = fmaf(w_s2 * fs_u0, k14 * y1c0, acc[2]);
                acc[3] = fmaf(w_s3 * fs_uB, k14 * y1cB, acc[3]);
                acc[4] = fmaf(w_s4 * fs_u2, k14 * y1c2, acc[4]);
                {
                    float e5 = (c0 == 0) ? fvB0 : (c0 == 1) ? fvB1 : fvB2;
                    float e6 = (cH == 0) ? fvH0 : (cH == 1) ? fvH1 : fvH2;
                    acc[5] = fmaf(w_s5 * e5, k14 * y0, acc[5]);
                    acc[6] = fmaf(w_s6 * e6, k14 * y0, acc[6]);
                }
                {
                    float cr7 = (c0 == 0) ? (fvB1 * y1z - fvB2 * y1y)
                              : (c0 == 1) ? (fvB2 * y1x - fvB0 * y1z)
                                          : (fvB0 * y1y - fvB1 * y1x);
                    float cr8 = (cH == 0) ? (fvH1 * y1z - fvH2 * y1y)
                              : (cH == 1) ? (fvH2 * y1x - fvH0 * y1z)
                                          : (fvH0 * y1y - fvH1 * y1x);
                    acc[7] = fmaf(w_s7 * cr7, k12, acc[7]);
                    acc[8] = fmaf(w_s8 * cr8, k12, acc[8]);
                }
            }
        }
    }

    if (node < Nn) {
        float* as = agg_s + (size_t)node * MIDS;
        float* av = agg_v + (size_t)node * (MIDV * 3);
        as[lane] = acc[0];
        if (half) as[64 + lane] = acc[1];
        av[lane]       = acc[2];
        av[64 + lane]  = acc[3];
        av[128 + lane] = acc[4];
        av[192 + lane] = acc[5];
        if (half) av[256 + lane] = acc[6];
        av[288 + lane] = acc[7];
        if (half) av[352 + lane] = acc[8];

        float avv = acc[0] * Wl3[lane];
        if (half) avv = fmaf(acc[1], Wl3[64 + lane], avv);
        #pragma unroll
        for (int d = 1; d < 64; d <<= 1) avv += __shfl_xor(avv, d);
        if (lane == 0) {
            float at = isbf ? ldf<true>(attr, node) : ldf<false>(attr, node);
            float a = 0.1f * avv * at;
            cosb[node] = __cosf(a);
            sinb[node] = __sinf(a);
        }
    }
}

// ---------------- k_final (fallback path only, u-major agg_v) --------------
template<bool BF>
__device__ __forceinline__ void final_body(
    const void* __restrict__ ns, const void* __restrict__ nv,
    const void* __restrict__ attr,
    const float* __restrict__ Wscs, const float* __restrict__ Wscv,
    const float* __restrict__ Wl2s, const float* __restrict__ Wl2v,
    const float* __restrict__ agg_s, const float* __restrict__ agg_v,
    const float* __restrict__ cosb, const float* __restrict__ sinb,
    void* __restrict__ out, int Nn)
{
    int i = blockIdx.x * 256 + threadIdx.x;
    int stotal = Nn * MUL0;
    if (i < stotal) {
        int n = i >> 6, j = i & 63;
        const float* ar = agg_s + (size_t)n * MIDS;
        float a1 = 0.f, a2 = 0.f;
        #pragma unroll
        for (int u = 0; u < MUL0; u++)
            a1 = fmaf(ldf<BF>(ns, (size_t)n * MUL0 + u), Wscs[u * MUL0 + j], a1);
        #pragma unroll
        for (int u = 0; u < MIDS; u++) a2 = fmaf(ar[u], Wl2s[u * MUL0 + j], a2);
        float o = ldf<BF>(attr, n) * (cosb[n] * a1 + sinb[n] * a2);
        stf<BF>(out, (size_t)n * 160 + j, o);
    } else {
        int m = i - stotal;
        if (m >= Nn * 96) return;
        int n = m / 96; int idx = m - n * 96;
        int vi = idx / 3; int c = idx - vi * 3;
        const float* ar = agg_v + (size_t)n * (MIDV * 3);
        float a1 = 0.f, a2 = 0.f;
        #pragma unroll
        for (int u = 0; u < MUL1; u++)
            a1 = fmaf(ldf<BF>(nv, (size_t)n * 96 + u * 3 + c), Wscv[u * MUL1 + vi], a1);
        #pragma unroll
        for (int u = 0; u < MIDV; u++) a2 = fmaf(ar[u * 3 + c], Wl2v[u * MUL1 + vi], a2);
        float o = ldf<BF>(attr, n) * (cosb[n] * a1 + sinb[n] * a2);
        stf<BF>(out, (size_t)n * 160 + 64 + idx, o);
    }
}
__global__ __launch_bounds__(256) void k_final(
    const void* ns, const void* nv, const void* attr,
    const float* Wscs, const float* Wscv,
    const float* Wl2s, const float* Wl2v,
    const float* agg_s, const float* agg_v,
    const float* cosb, const float* sinb,
    void* out, int Nn, const int* flag)
{
    if (*flag) final_body<true >(ns, nv, attr, Wscs, Wscv, Wl2s, Wl2v, agg_s, agg_v, cosb, sinb, out, Nn);
    else       final_body<false>(ns, nv, attr, Wscs, Wscv, Wl2s, Wl2v, agg_s, agg_v, cosb, sinb, out, Nn);
}

// ---------------- launch ----------------
extern "C" void kernel_launch(void* const* d_in, const int* in_sizes, int n_in,
                              void* d_out, int out_size, void* d_ws, size_t ws_size,
                              hipStream_t stream)
{
    const void* ns    = d_in[0];
    const void* nv    = d_in[1];
    const void* attr  = d_in[2];
    const int*  esrc  = (const int*)d_in[3];
    const int*  edst  = (const int*)d_in[4];
    const void* eattr = d_in[5];
    const void* escal = d_in[6];

    const int Nn   = in_sizes[2];
    const int Ecnt = in_sizes[3];

    float* ws = (float*)d_ws;
    int* flag = (int*)(ws + OFF_FLAG);
    unsigned short* w1frag = (unsigned short*)(ws + OFF_W1FRAG);
    unsigned short* w2frag = (unsigned short*)(ws + OFF_W2FRAG);

    size_t o = OFF_DYN;
    const size_t OFF_FS   = o; o += (size_t)Nn * 64;
    const size_t OFF_FV   = o; o += (size_t)Nn * 96;
    const size_t OFF_AGGS = o; o += (size_t)Nn * 96;    // agg_s (both paths)
    const size_t OFF_AGGV = o; o += (size_t)Nn * 384;   // split: c-major | fallback: u-major
    const size_t OFF_COS  = o; o += Nn;
    const size_t OFF_SIN  = o; o += Nn;
    const size_t OFF_CNT  = o; o += Nn;
    const size_t OFF_ROW  = o; o += Nn + 1;
    const size_t OFF_CUR  = o; o += Nn;
    const size_t OFF_RPART= o; o += Nn;
    const size_t OFF_BSUM = o; o += 256;
    const size_t OFF_BOFF = o; o += 256;
    const size_t OFF_PERM = o; o += Ecnt;
    const size_t OFF_SRCS = o; o += Ecnt;
    o = (o + 3) & ~(size_t)3;
    const size_t OFF_Y4   = o; o += (size_t)Ecnt * 4;
    o = (o + 15) & ~(size_t)15;
    const size_t OFF_WBUF = o;
    const int tiles = (Ecnt + 127) / 128;           // 128-edge k_fc tiles
    o += (size_t)tiles * 128 * 112;                 // 224 ushorts = 112 floats per row
    const size_t need_bytes = o * sizeof(float);

    int* cnt       = (int*)(ws + OFF_CNT);
    int* row_start = (int*)(ws + OFF_ROW);
    int* cur       = (int*)(ws + OFF_CUR);
    int* row_part  = (int*)(ws + OFF_RPART);
    int* blk_sum   = (int*)(ws + OFF_BSUM);
    int* blk_off   = (int*)(ws + OFF_BOFF);
    int* perm      = (int*)(ws + OFF_PERM);
    int* srcs      = (int*)(ws + OFF_SRCS);
    float* y4      = ws + OFF_Y4;
    unsigned short* wbuf = (unsigned short*)(ws + OFF_WBUF);

    const int NB = (Nn + 255) / 256;
    const bool split = (ws_size >= need_bytes) && (NB <= 256);

    // prep: probe + convert + frag build + cnt zero (node precompute moved
    // to k_pre_s / k_pre_v GEMM kernels)
    const int prep_work = OFF_WEND + W1FRAG_N + W2FRAG_N + Nn;
    k_prep<<<(prep_work + 255) / 256, 256, 0, stream>>>(
        attr,
        d_in[7], d_in[8], d_in[9], d_in[10], d_in[11], d_in[12],
        d_in[13], d_in[14], d_in[15],
        ws, w1frag, w2frag, cnt, flag, Nn);

    k_pre_s<<<(Nn + 31) / 32, 256, 0, stream>>>(
        ns, attr, ws + OFF_WL1S, ws + OFF_FS, Nn);
    k_pre_v<<<(3 * Nn + 63) / 64, 256, 0, stream>>>(
        nv, attr, ws + OFF_WL1V, ws + OFF_FV, Nn);

    k_hist<<<(Ecnt + 255) / 256, 256, 0, stream>>>(edst, cnt, Ecnt);

    if (split) {
        k_scan_blk<<<NB, 256, 0, stream>>>(cnt, row_part, blk_sum, Nn);
        k_scan_top<<<1, 256, 0, stream>>>(blk_sum, blk_off, row_start, NB, Nn);
        k_rowfix<<<NB, 256, 0, stream>>>(row_part, blk_off, row_start, cur, Nn);
        k_place<<<(Ecnt + 255) / 256, 256, 0, stream>>>(
            edst, esrc, eattr, row_start, cur, perm, srcs, y4, Ecnt, flag, 1);

        k_fc<<<tiles, 256, 0, stream>>>(escal, perm, w1frag, w2frag, wbuf, Ecnt, flag);

        k_agg<<<(Nn + EG - 1) / EG, 256, 0, stream>>>(
            wbuf, srcs, y4, row_start,
            ws + OFF_FS, ws + OFF_FV, ws + OFF_WL3, attr,
            ws + OFF_AGGS, ws + OFF_AGGV, ws + OFF_COS, ws + OFF_SIN,
            Nn, flag);

        k_final_s<<<(Nn + 31) / 32, 256, 0, stream>>>(
            ws + OFF_AGGS, ns, ws + OFF_WSCS, ws + OFF_WL2S,
            ws + OFF_COS, ws + OFF_SIN, attr, (void*)d_out, Nn, flag);
        k_final_v<<<(3 * Nn + 63) / 64, 256, 0, stream>>>(
            ws + OFF_AGGV, nv, ws + OFF_WSCV, ws + OFF_WL2V,
            ws + OFF_COS, ws + OFF_SIN, attr, (void*)d_out, Nn, flag);
    } else {
        k_scan1<<<1, 1024, 0, stream>>>(cnt, row_start, cur, Nn);
        k_place<<<(Ecnt + 255) / 256, 256, 0, stream>>>(
            edst, esrc, eattr, row_start, cur, perm, srcs, y4, Ecnt, flag, 0);
        k_edge_mfma<<<(Nn + EG - 1) / EG, 256, 0, stream>>>(
            escal, eattr, attr, esrc, row_start, perm, w1frag, w2frag,
            ws + OFF_WL3,
            ws + OFF_FS, ws + OFF_FV,
            ws + OFF_AGGS, ws + OFF_AGGV, ws + OFF_COS, ws + OFF_SIN,
            Nn, flag);
        k_final<<<((Nn * 160) + 255) / 256, 256, 0, stream>>>(
            ns, nv, attr,
            ws + OFF_WSCS, ws + OFF_WSCV, ws + OFF_WL2S, ws + OFF_WL2V,
            ws + OFF_AGGS, ws + OFF_AGGV, ws + OFF_COS, ws + OFF_SIN,
            (void*)d_out, Nn, flag);
    }
}

// Round 11
// 483.129 us; speedup vs baseline: 1.0458x; 1.0458x over previous
//
#include <hip/hip_runtime.h>

// ---------------- problem constants ----------------
#define MUL0 64
#define MUL1 32
#define NBASIS 10
#define FCH 100
#define WNUMEL 224   // 2*MUL0 + 3*MUL1
#define MIDS 96      // MUL0 + MUL1
#define MIDV 128     // MUL0 + 2*MUL1
#define EG 4         // dst nodes per workgroup (one per wave)

// weight table offsets inside ws (floats), in d_in[7..15] order
#define OFF_W1   0        // W_fc1  10x100  (1000)
#define OFF_W2   1000     // W_fc2  100x224 (22400)
#define OFF_WSCS 23400    // W_sc_s 64x64   (4096)
#define OFF_WSCV 27496    // W_sc_v 32x32   (1024)
#define OFF_WL1S 28520    // W_l1_s 64x64   (4096)
#define OFF_WL1V 32616    // W_l1_v 32x32   (1024)
#define OFF_WL2S 33640    // W_l2_s 96x64   (6144)
#define OFF_WL2V 39784    // W_l2_v 128x32  (4096)
#define OFF_WL3  43880    // W_l3   96x1    (96)
#define OFF_WEND 43976
#define OFF_FLAG 43980    // dtype flag (int)
#define OFF_W1FRAG 44032  // bf16 frag layout, 3584 ushorts = 1792 floats
#define OFF_W2FRAG 45824  // bf16 frag layout, 28672 ushorts = 14336 floats
#define OFF_DYN  60160    // start of per-node buffers

#define W1FRAG_N (112 * 32)       // 3584
#define W2FRAG_N (4 * 224 * 32)   // 28672

typedef __attribute__((ext_vector_type(8))) short short8;
typedef __attribute__((ext_vector_type(4))) float f32x4;

// ---------------- helpers ----------------
__device__ __forceinline__ float bf2f(unsigned short h) {
    unsigned int u = ((unsigned int)h) << 16;
    float f; __builtin_memcpy(&f, &u, 4); return f;
}
__device__ __forceinline__ unsigned short f2bf(float f) {
    unsigned int u; __builtin_memcpy(&u, &f, 4);
    u += 0x7fffu + ((u >> 16) & 1u);   // round-to-nearest-even
    return (unsigned short)(u >> 16);
}
__device__ __forceinline__ float fast_silu(float x) {
    return x * __builtin_amdgcn_rcpf(1.0f + __expf(-x));
}
template<bool BF>
__device__ __forceinline__ float ldf(const void* p, size_t i) {
    if constexpr (BF) return bf2f(((const unsigned short*)p)[i]);
    else              return ((const float*)p)[i];
}
template<bool BF>
__device__ __forceinline__ void stf(void* p, size_t i, float v) {
    if constexpr (BF) ((unsigned short*)p)[i] = f2bf(v);
    else              ((float*)p)[i] = v;
}
// 4 consecutive elements starting at 4-aligned index i -> f32x4
template<bool BF>
__device__ __forceinline__ f32x4 ld4(const void* p, size_t i) {
    if constexpr (BF) {
        ushort4 h = *(const ushort4*)((const unsigned short*)p + i);
        return (f32x4){bf2f(h.x), bf2f(h.y), bf2f(h.z), bf2f(h.w)};
    } else {
        return *(const f32x4*)((const float*)p + i);
    }
}
__device__ __forceinline__ int wave_incl_scan(int v) {
    int lane = threadIdx.x & 63;
    #pragma unroll
    for (int d = 1; d < 64; d <<= 1) {
        int t = __shfl_up(v, d, 64);
        if (lane >= d) v += t;
    }
    return v;
}

// ---------------- k_prep: probe + convert + frag build + cnt zero ----------
__global__ __launch_bounds__(256) void k_prep(
    const void* __restrict__ attr,
    const void* __restrict__ a0, const void* __restrict__ a1,
    const void* __restrict__ a2, const void* __restrict__ a3,
    const void* __restrict__ a4, const void* __restrict__ a5,
    const void* __restrict__ a6, const void* __restrict__ a7,
    const void* __restrict__ a8,
    float* __restrict__ wsf,
    unsigned short* __restrict__ w1frag, unsigned short* __restrict__ w2frag,
    int* __restrict__ cnt, int* __restrict__ flag, int Nn)
{
    const bool bf = (((const unsigned int*)attr)[0] == 0x3F803F80u);
    int m = blockIdx.x * 256 + threadIdx.x;
    if (m == 0) *flag = bf ? 1 : 0;

    if (m < OFF_WEND) {
        const void* p; int off = m;
        if      (m < OFF_W2)   { p = a0; }
        else if (m < OFF_WSCS) { p = a1; off = m - OFF_W2; }
        else if (m < OFF_WSCV) { p = a2; off = m - OFF_WSCS; }
        else if (m < OFF_WL1S) { p = a3; off = m - OFF_WSCV; }
        else if (m < OFF_WL1V) { p = a4; off = m - OFF_WL1S; }
        else if (m < OFF_WL2S) { p = a5; off = m - OFF_WL1V; }
        else if (m < OFF_WL2V) { p = a6; off = m - OFF_WL2S; }
        else if (m < OFF_WL3)  { p = a7; off = m - OFF_WL2V; }
        else                   { p = a8; off = m - OFF_WL3; }
        wsf[m] = bf ? ldf<true>(p, off) : ldf<false>(p, off);
        return;
    }
    m -= OFF_WEND;
    if (m < W1FRAG_N) {
        int col = m >> 5, k = m & 31;
        float v = 0.f;
        if (col < FCH && k < NBASIS)
            v = bf ? ldf<true>(a0, k * FCH + col) : ldf<false>(a0, k * FCH + col);
        w1frag[m] = f2bf(v);
        return;
    }
    m -= W1FRAG_N;
    if (m < W2FRAG_N) {
        int q = m / (224 * 32); int r = m - q * 224 * 32;
        int n = r >> 5; int kk = r & 31;
        int k = q * 32 + kk;
        float v = 0.f;
        if (k < FCH)
            v = bf ? ldf<true>(a1, k * WNUMEL + n) : ldf<false>(a1, k * WNUMEL + n);
        w2frag[m] = f2bf(v);
        return;
    }
    m -= W2FRAG_N;
    if (m < Nn) cnt[m] = 0;
}

// ---------------- k_pre: fused node precompute (s-blocks + v-blocks) -------
// f_s[n][64] = (ns[n][:] @ W_l1_s) * attr[n]
// f_v[n][u][c] = (sum_k nv[n][k][c] W_l1_v[k][u]) * attr[n]
#define PS_STRIDE 68   // 272 B rows, 17 granules (odd) -> conflict-free b128
#define PV_STRIDE 36   // 144 B rows, 9 granules (odd)

template<bool BF>
__device__ __forceinline__ void pre_s_body(
    const void* __restrict__ ns, const void* __restrict__ attr,
    const float* Wt, float* __restrict__ f_s, int Nn, int lane, int nb)
{
    float acc[8]; int nidx[8];
    #pragma unroll
    for (int r = 0; r < 8; r++) {
        acc[r] = 0.f;
        int n = nb + r; nidx[r] = (n < Nn) ? n : (Nn - 1);
    }
    #pragma unroll 2
    for (int t = 0; t < 16; t++) {
        f32x4 wv = *(const f32x4*)&Wt[lane * PS_STRIDE + 4 * t];
        #pragma unroll
        for (int r = 0; r < 8; r++) {
            f32x4 x = ld4<BF>(ns, (size_t)nidx[r] * 64 + 4 * t);
            acc[r] = fmaf(x[0], wv[0], acc[r]);
            acc[r] = fmaf(x[1], wv[1], acc[r]);
            acc[r] = fmaf(x[2], wv[2], acc[r]);
            acc[r] = fmaf(x[3], wv[3], acc[r]);
        }
    }
    #pragma unroll
    for (int r = 0; r < 8; r++) {
        int n = nb + r;
        if (n < Nn) {
            float at = ldf<BF>(attr, n);
            f_s[(size_t)n * 64 + lane] = acc[r] * at;
        }
    }
}

template<bool BF>
__device__ __forceinline__ void pre_v_body(
    const void* __restrict__ nv, const void* __restrict__ attr,
    const float* Wt, float* __restrict__ f_v, int Nn, int lane, int ub)
{
    const int vi  = lane & 31;
    const int grp = lane >> 5;
    const int NU  = 3 * Nn;
    float acc[8]; int nn_[8], cc_[8];
    #pragma unroll
    for (int r = 0; r < 8; r++) {
        acc[r] = 0.f;
        int g = ub + grp * 8 + r;
        if (g > NU - 1) g = NU - 1;
        nn_[r] = (int)((unsigned)g / 3u);
        cc_[r] = g - 3 * nn_[r];
    }
    #pragma unroll 2
    for (int t = 0; t < 8; t++) {
        f32x4 wv = *(const f32x4*)&Wt[vi * PV_STRIDE + 4 * t];
        #pragma unroll
        for (int r = 0; r < 8; r++) {
            size_t b = (size_t)nn_[r] * 96 + (size_t)(4 * t) * 3 + cc_[r];
            float x0 = ldf<BF>(nv, b);
            float x1 = ldf<BF>(nv, b + 3);
            float x2 = ldf<BF>(nv, b + 6);
            float x3 = ldf<BF>(nv, b + 9);
            acc[r] = fmaf(x0, wv[0], acc[r]);
            acc[r] = fmaf(x1, wv[1], acc[r]);
            acc[r] = fmaf(x2, wv[2], acc[r]);
            acc[r] = fmaf(x3, wv[3], acc[r]);
        }
    }
    #pragma unroll
    for (int r = 0; r < 8; r++) {
        int g = ub + grp * 8 + r;
        if (g < NU) {
            int n = nn_[r], c = cc_[r];
            float at = ldf<BF>(attr, n);
            f_v[(size_t)n * 96 + vi * 3 + c] = acc[r] * at;
        }
    }
}

__global__ __launch_bounds__(256) void k_pre(
    const void* __restrict__ ns, const void* __restrict__ nv,
    const void* __restrict__ attr,
    const float* __restrict__ Wl1s, const float* __restrict__ Wl1v,
    float* __restrict__ f_s, float* __restrict__ f_v, int Nn, int gridS)
{
    __shared__ float Wt[64 * PS_STRIDE];   // 17408 B (v path uses a prefix)
    const int tid = threadIdx.x;
    const bool bf = (((const unsigned int*)attr)[0] == 0x3F803F80u);
    const int lane = tid & 63;
    const int wave = __builtin_amdgcn_readfirstlane(tid >> 6);

    if ((int)blockIdx.x < gridS) {
        for (int i = tid; i < 64 * 64; i += 256) {
            int u = i >> 6, j = i & 63;
            Wt[j * PS_STRIDE + u] = Wl1s[u * 64 + j];
        }
        __syncthreads();
        const int nb = ((int)blockIdx.x * 4 + wave) * 8;
        if (nb >= Nn) return;
        if (bf) pre_s_body<true >(ns, attr, Wt, f_s, Nn, lane, nb);
        else    pre_s_body<false>(ns, attr, Wt, f_s, Nn, lane, nb);
    } else {
        const int vb = (int)blockIdx.x - gridS;
        for (int i = tid; i < 32 * 32; i += 256) {
            int u = i >> 5, vi = i & 31;
            Wt[vi * PV_STRIDE + u] = Wl1v[u * 32 + vi];
        }
        __syncthreads();
        const int ub = (vb * 4 + wave) * 16;
        if (ub >= 3 * Nn) return;
        if (bf) pre_v_body<true >(nv, attr, Wt, f_v, Nn, lane, ub);
        else    pre_v_body<false>(nv, attr, Wt, f_v, Nn, lane, ub);
    }
}

// ---------------- CSR: histogram ----------------
__global__ __launch_bounds__(256) void k_hist(
    const int* __restrict__ edst, int* __restrict__ cnt, int Ecnt)
{
    int e = blockIdx.x * 256 + threadIdx.x;
    if (e < Ecnt) atomicAdd(&cnt[edst[e]], 1);
}

// ---------------- 3-phase parallel scan ----------
__global__ __launch_bounds__(256) void k_scan_blk(
    const int* __restrict__ cnt, int* __restrict__ row_part,
    int* __restrict__ blk_sum, int Nn)
{
    __shared__ int ws4[4];
    int tid = threadIdx.x, lane = tid & 63, wid = tid >> 6;
    int i = blockIdx.x * 256 + tid;
    int v = (i < Nn) ? cnt[i] : 0;
    int incl = wave_incl_scan(v);
    if (lane == 63) ws4[wid] = incl;
    __syncthreads();
    int off = 0;
    #pragma unroll
    for (int w2 = 0; w2 < 4; w2++) off += (w2 < wid) ? ws4[w2] : 0;
    if (i < Nn) row_part[i] = off + incl - v;
    if (tid == 0) blk_sum[blockIdx.x] = ws4[0] + ws4[1] + ws4[2] + ws4[3];
}

__global__ __launch_bounds__(256) void k_scan_top(
    const int* __restrict__ blk_sum, int* __restrict__ blk_off,
    int* __restrict__ row_start, int NB, int Nn)
{
    __shared__ int ws4[4];
    int tid = threadIdx.x, lane = tid & 63, wid = tid >> 6;
    int v = (tid < NB) ? blk_sum[tid] : 0;
    int incl = wave_incl_scan(v);
    if (lane == 63) ws4[wid] = incl;
    __syncthreads();
    int off = 0;
    #pragma unroll
    for (int w2 = 0; w2 < 4; w2++) off += (w2 < wid) ? ws4[w2] : 0;
    if (tid < NB) blk_off[tid] = off + incl - v;
    if (tid == 0) row_start[Nn] = ws4[0] + ws4[1] + ws4[2] + ws4[3];
}

__global__ __launch_bounds__(256) void k_rowfix(
    const int* __restrict__ row_part, const int* __restrict__ blk_off,
    int* __restrict__ row_start, int* __restrict__ cur, int Nn)
{
    int i = blockIdx.x * 256 + threadIdx.x;
    if (i < Nn) { row_start[i] = blk_off[i >> 8] + row_part[i]; cur[i] = 0; }
}

// ---------------- fallback single-wg scan (old path) ----------------
__global__ __launch_bounds__(1024) void k_scan1(
    const int* __restrict__ cnt, int* __restrict__ row_start,
    int* __restrict__ cur, int Nn)
{
    __shared__ int wsum[16];
    __shared__ int s_off, s_tot;
    int tid = threadIdx.x, lane = tid & 63, wid = tid >> 6;
    if (tid == 0) s_off = 0;
    __syncthreads();
    for (int base = 0; base < Nn; base += 1024) {
        int i = base + tid;
        int v = (i < Nn) ? cnt[i] : 0;
        int incl = wave_incl_scan(v);
        if (lane == 63) wsum[wid] = incl;
        __syncthreads();
        if (wid == 0) {
            int wv = (lane < 16) ? wsum[lane] : 0;
            int wincl = wave_incl_scan(wv);
            if (lane < 16) wsum[lane] = wincl - wv;
            if (lane == 15) s_tot = wincl;
        }
        __syncthreads();
        int excl = s_off + wsum[wid] + incl - v;
        if (i < Nn) { row_start[i] = excl; cur[i] = 0; }
        __syncthreads();
        if (tid == 0) s_off += s_tot;
        __syncthreads();
    }
    if (threadIdx.x == 0) row_start[Nn] = s_off;
}

// ---------------- k_place ----------------
__global__ __launch_bounds__(256) void k_place(
    const int* __restrict__ edst, const int* __restrict__ esrc,
    const void* __restrict__ eattr,
    const int* __restrict__ row_start, int* __restrict__ cur,
    int* __restrict__ perm, int* __restrict__ srcs, float* __restrict__ y4,
    int Ecnt, const int* __restrict__ flag, int extras)
{
    int e = blockIdx.x * 256 + threadIdx.x;
    if (e >= Ecnt) return;
    int d = edst[e];
    int pos = row_start[d] + atomicAdd(&cur[d], 1);
    perm[pos] = e;
    if (extras) {
        srcs[pos] = esrc[e];
        float4 yv;
        if (*flag) {
            const unsigned short* ap = (const unsigned short*)eattr + (size_t)e * 4;
            yv = make_float4(bf2f(ap[0]), bf2f(ap[1]), bf2f(ap[2]), bf2f(ap[3]));
        } else {
            const float* ap = (const float*)eattr + (size_t)e * 4;
            yv = make_float4(ap[0], ap[1], ap[2], ap[3]);
        }
        ((float4*)y4)[pos] = yv;
    }
}

// ---------------- k_fc: dense per-edge MLP (MFMA), edge-major wbuf ---------
// FC2 is COLUMN-SPLIT across waves: wave w owns t-tiles (4,4,3,3 split) and
// reuses each B-fragment across the 4 edge-groups (A rows come from the
// block-shared h_lds) -> 4x less w2frag L2 traffic than edge-split.
#define HFC_STRIDE 136   // 272 B rows, 16B-aligned

__global__ __launch_bounds__(256) void k_fc(
    const void* __restrict__ escal, const int* __restrict__ perm,
    const unsigned short* __restrict__ w1frag, const unsigned short* __restrict__ w2frag,
    unsigned short* __restrict__ wbuf, int Ecnt, const int* __restrict__ flag)
{
    __shared__ __align__(16) unsigned short h_lds[64 * HFC_STRIDE]; // 17.4 KB
    const int tid  = threadIdx.x;
    const int lane = tid & 63;
    const int wave = tid >> 6;
    const int nl   = lane & 15;
    const int quad = lane >> 4;
    const int tb   = blockIdx.x * 64;

    // zero h padding cols 112..127
    for (int i = tid; i < 64 * 16; i += 256) {
        int row = i >> 4;
        h_lds[row * HFC_STRIDE + 112 + (i & 15)] = 0;
    }

    // load es A-fragment straight from global (k rows 10..31 are zero)
    int eidx = tb + 16 * wave + nl;
    if (eidx >= Ecnt) eidx = Ecnt - 1;
    const int e = perm[eidx];
    short8 a = {0, 0, 0, 0, 0, 0, 0, 0};
    if (*flag) {
        const unsigned int* p = (const unsigned int*)((const unsigned short*)escal + (size_t)e * NBASIS);
        if (quad == 0) {
            unsigned int d0 = p[0], d1 = p[1], d2 = p[2], d3 = p[3];
            a = (short8){(short)d0, (short)(d0 >> 16), (short)d1, (short)(d1 >> 16),
                         (short)d2, (short)(d2 >> 16), (short)d3, (short)(d3 >> 16)};
        } else if (quad == 1) {
            unsigned int d4 = p[4];
            a = (short8){(short)d4, (short)(d4 >> 16), 0, 0, 0, 0, 0, 0};
        }
    } else {
        const float* p = (const float*)escal + (size_t)e * NBASIS;
        if (quad == 0) {
            a = (short8){(short)f2bf(p[0]), (short)f2bf(p[1]), (short)f2bf(p[2]), (short)f2bf(p[3]),
                         (short)f2bf(p[4]), (short)f2bf(p[5]), (short)f2bf(p[6]), (short)f2bf(p[7])};
        } else if (quad == 1) {
            a = (short8){(short)f2bf(p[8]), (short)f2bf(p[9]), 0, 0, 0, 0, 0, 0};
        }
    }

    // FC1: 7 col-tiles
    {
        f32x4 hacc[7];
        #pragma unroll
        for (int t = 0; t < 7; t++) {
            short8 b = *(const short8*)&w1frag[(16 * t + nl) * 32 + quad * 8];
            hacc[t] = __builtin_amdgcn_mfma_f32_16x16x32_bf16(
                a, b, (f32x4){0.f, 0.f, 0.f, 0.f}, 0, 0, 0);
        }
        #pragma unroll
        for (int t = 0; t < 7; t++) {
            #pragma unroll
            for (int r = 0; r < 4; r++)
                h_lds[(16 * wave + quad * 4 + r) * HFC_STRIDE + 16 * t + nl] =
                    f2bf(fast_silu(hacc[t][r]));
        }
    }
    __syncthreads();

    // FC2 column-split: wave owns t-tiles, B-fragments reused across 4
    // edge-groups. tsta/tend: waves 0,1 -> 4 tiles; waves 2,3 -> 3 tiles.
    {
        const int tsta = (wave < 2) ? wave * 4 : 8 + (wave - 2) * 3;
        const int tend = (wave < 2) ? tsta + 4 : tsta + 3;
        for (int t = tsta; t < tend; t++) {
            short8 b0 = *(const short8*)&w2frag[(0 * 224 + 16 * t + nl) * 32 + quad * 8];
            short8 b1 = *(const short8*)&w2frag[(1 * 224 + 16 * t + nl) * 32 + quad * 8];
            short8 b2 = *(const short8*)&w2frag[(2 * 224 + 16 * t + nl) * 32 + quad * 8];
            short8 b3 = *(const short8*)&w2frag[(3 * 224 + 16 * t + nl) * 32 + quad * 8];
            #pragma unroll
            for (int eg = 0; eg < 4; eg++) {
                const unsigned short* hrow = &h_lds[(16 * eg + nl) * HFC_STRIDE];
                f32x4 c = {0.f, 0.f, 0.f, 0.f};
                c = __builtin_amdgcn_mfma_f32_16x16x32_bf16(
                    *(const short8*)&hrow[0 * 32 + quad * 8], b0, c, 0, 0, 0);
                c = __builtin_amdgcn_mfma_f32_16x16x32_bf16(
                    *(const short8*)&hrow[1 * 32 + quad * 8], b1, c, 0, 0, 0);
                c = __builtin_amdgcn_mfma_f32_16x16x32_bf16(
                    *(const short8*)&hrow[2 * 32 + quad * 8], b2, c, 0, 0, 0);
                c = __builtin_amdgcn_mfma_f32_16x16x32_bf16(
                    *(const short8*)&hrow[3 * 32 + quad * 8], b3, c, 0, 0, 0);
                #pragma unroll
                for (int r = 0; r < 4; r++)
                    wbuf[(size_t)(tb + 16 * eg + quad * 4 + r) * WNUMEL + 16 * t + nl] =
                        f2bf(c[r]);
            }
        }
    }
}

// ---------------- k_agg: one wave per dst; FOUR chains, zero shuffles ------
// agg_s[n][96] coalesced; agg_v stored C-MAJOR: aggv[n*384 + c*128 + u]
// Quarter-split chains, branch-free: invalid indices clamp to dhi-1 and the
// y-vector is zeroed, nullifying every accumulation term (all terms carry a
// y factor on their live path).
__global__ __launch_bounds__(256) void k_agg(
    const unsigned short* __restrict__ wbuf,
    const int* __restrict__ srcs, const float* __restrict__ y4,
    const int* __restrict__ row_start,
    const float* __restrict__ f_s, const float* __restrict__ f_v,
    const float* __restrict__ Wl3, const void* __restrict__ attr,
    float* __restrict__ agg_s, float* __restrict__ aggv,
    float* __restrict__ cosb, float* __restrict__ sinb,
    int Nn, const int* __restrict__ flag)
{
    const int tid  = threadIdx.x;
    const int lane = tid & 63;
    const int wave = tid >> 6;
    const int node = blockIdx.x * EG + wave;
    if (node >= Nn) return;

    const int lane2 = lane & 31;
    const bool hi = (lane >= 32);

    const int dlo = row_start[node];
    const int dhi = row_start[node + 1];
    const int deg = dhi - dlo;
    const int q   = (deg + 3) >> 2;

    const float k14 = 0.25f;
    const float k13 = 0.25f * 0.57735026918962576451f;
    const float k12 = 0.25f * 0.70710678118654752440f;

    float A0[4], A1[4], S0[4], S1[4], S2[4], V0[4], V1[4], V2[4];
    #pragma unroll
    for (int c = 0; c < 4; c++) {
        A0[c] = A1[c] = S0[c] = S1[c] = S2[c] = V0[c] = V1[c] = V2[c] = 0.f;
    }

    for (int j = 0; j < q; j++) {
        #pragma unroll
        for (int c = 0; c < 4; c++) {
            const int idxr = dlo + c * q + j;
            const int idx_ = (idxr < dhi) ? idxr : (dhi - 1);
            const float vm = (idxr < dhi) ? 1.f : 0.f;
            const int srcn = srcs[idx_];
            const float4 y = ((const float4*)y4)[idx_];
            const float y0 = y.x * vm, y1x = y.y * vm, y1y = y.z * vm, y1z = y.w * vm;
            const unsigned short* wrow = wbuf + (size_t)idx_ * WNUMEL;
            const float* fsr = f_s + (size_t)srcn * 64;
            const float* fvr = f_v + (size_t)srcn * 96;
            float fs_l = fsr[lane];
            float v0 = fvr[lane2 * 3 + 0];
            float v1 = fvr[lane2 * 3 + 1];
            float v2 = fvr[lane2 * 3 + 2];
            float w00 = bf2f(wrow[lane]);
            float w01 = bf2f(wrow[64 + lane]);
            float wh  = bf2f(wrow[128 + lane]);
            float wx  = bf2f(wrow[160 + lane]);

            A0[c] = fmaf(w00 * fs_l, y0 * k14, A0[c]);
            float dot_ = v0 * y1x + v1 * y1y + v2 * y1z;
            A1[c] = fmaf(wh * dot_, k13, A1[c]);
            float t1_ = w01 * fs_l * k14;
            S0[c] = fmaf(t1_, y1x, S0[c]);
            S1[c] = fmaf(t1_, y1y, S1[c]);
            S2[c] = fmaf(t1_, y1z, S2[c]);
            float cx_ = v1 * y1z - v2 * y1y;
            float cy_ = v2 * y1x - v0 * y1z;
            float cz_ = v0 * y1y - v1 * y1x;
            float e0_ = hi ? cx_ : v0;
            float e1_ = hi ? cy_ : v1;
            float e2_ = hi ? cz_ : v2;
            float tv_ = hi ? (wx * k12) : (wh * (y0 * k14));
            V0[c] = fmaf(e0_, tv_, V0[c]);
            V1[c] = fmaf(e1_, tv_, V1[c]);
            V2[c] = fmaf(e2_, tv_, V2[c]);
        }
    }

    const float acc0  = (A0[0] + A0[1]) + (A0[2] + A0[3]);
    const float acc1  = (A1[0] + A1[1]) + (A1[2] + A1[3]);
    const float accS0 = (S0[0] + S0[1]) + (S0[2] + S0[3]);
    const float accS1 = (S1[0] + S1[1]) + (S1[2] + S1[3]);
    const float accS2 = (S2[0] + S2[1]) + (S2[2] + S2[3]);
    const float accV0 = (V0[0] + V0[1]) + (V0[2] + V0[3]);
    const float accV1 = (V1[0] + V1[1]) + (V1[2] + V1[3]);
    const float accV2 = (V2[0] + V2[1]) + (V2[2] + V2[3]);

    // writeback: agg_s coalesced; aggv c-major; angle -> cos/sin
    {
        float* as = agg_s + (size_t)node * MIDS;
        float* av = aggv  + (size_t)node * 384;
        as[lane] = acc0;
        if (hi) as[64 + lane2] = acc1;

        av[0 * 128 + lane] = accS0;
        av[1 * 128 + lane] = accS1;
        av[2 * 128 + lane] = accS2;
        const int vrow = hi ? (96 + lane2) : (64 + lane);
        av[0 * 128 + vrow] = accV0;
        av[1 * 128 + vrow] = accV1;
        av[2 * 128 + vrow] = accV2;

        float avv = acc0 * Wl3[lane];
        if (hi) avv = fmaf(acc1, Wl3[64 + lane2], avv);
        #pragma unroll
        for (int d = 1; d < 64; d <<= 1) avv += __shfl_xor(avv, d);
        if (lane == 0) {
            float at = (*flag) ? ldf<true>(attr, node) : ldf<false>(attr, node);
            float aa = 0.1f * avv * at;
            cosb[node] = __cosf(aa);
            sinb[node] = __sinf(aa);
        }
    }
}

// ---------------- k_final_s / k_final_v: LDS-weight register-blocked GEMMs -
// Wt row stride 164 floats = 656 B = 41 (odd) 16B-granules -> within any
// 16-lane phase the granule index == 41*lane mod 8 covers all 8 slots twice
// -> <=2-way LDS access on ds_read_b128 (free, m136).
#define WT_STRIDE 164

template<bool BF>
__device__ __forceinline__ void final_s_body(
    const float* __restrict__ agg_s, const void* __restrict__ ns,
    const float* __restrict__ cosb, const float* __restrict__ sinb,
    const void* __restrict__ attr, void* __restrict__ out,
    int Nn, const float* Wt, int lane, int nb)
{
    float acc_sc[8], acc_l2[8];
    int nidx[8];
    #pragma unroll
    for (int r = 0; r < 8; r++) {
        acc_sc[r] = 0.f; acc_l2[r] = 0.f;
        int n = nb + r; nidx[r] = (n < Nn) ? n : (Nn - 1);
    }
    // sc part: u = 0..63 from ns
    #pragma unroll 2
    for (int t = 0; t < 16; t++) {
        f32x4 wv = *(const f32x4*)&Wt[lane * WT_STRIDE + 4 * t];
        #pragma unroll
        for (int r = 0; r < 8; r++) {
            f32x4 x = ld4<BF>(ns, (size_t)nidx[r] * 64 + 4 * t);
            acc_sc[r] = fmaf(x[0], wv[0], acc_sc[r]);
            acc_sc[r] = fmaf(x[1], wv[1], acc_sc[r]);
            acc_sc[r] = fmaf(x[2], wv[2], acc_sc[r]);
            acc_sc[r] = fmaf(x[3], wv[3], acc_sc[r]);
        }
    }
    // l2 part: u = 0..95 from agg_s
    #pragma unroll 2
    for (int t = 0; t < 24; t++) {
        f32x4 wv = *(const f32x4*)&Wt[lane * WT_STRIDE + 64 + 4 * t];
        #pragma unroll
        for (int r = 0; r < 8; r++) {
            f32x4 x = *(const f32x4*)(agg_s + (size_t)nidx[r] * 96 + 4 * t);
            acc_l2[r] = fmaf(x[0], wv[0], acc_l2[r]);
            acc_l2[r] = fmaf(x[1], wv[1], acc_l2[r]);
            acc_l2[r] = fmaf(x[2], wv[2], acc_l2[r]);
            acc_l2[r] = fmaf(x[3], wv[3], acc_l2[r]);
        }
    }
    #pragma unroll
    for (int r = 0; r < 8; r++) {
        int n = nb + r;
        if (n < Nn) {
            float cv = cosb[n], sv = sinb[n];
            float at = ldf<BF>(attr, n);
            stf<BF>(out, (size_t)n * 160 + lane, at * (cv * acc_sc[r] + sv * acc_l2[r]));
        }
    }
}

__global__ __launch_bounds__(256) void k_final_s(
    const float* __restrict__ agg_s, const void* __restrict__ ns,
    const float* __restrict__ Wscs, const float* __restrict__ Wl2s,
    const float* __restrict__ cosb, const float* __restrict__ sinb,
    const void* __restrict__ attr, void* __restrict__ out,
    int Nn, const int* __restrict__ flag)
{
    __shared__ float Wt[64 * WT_STRIDE];   // 41984 B
    const int tid = threadIdx.x;
    // Wt[j][u]: u<64 -> Wscs[u][j]; u>=64 -> Wl2s[u-64][j]
    for (int i = tid; i < 160 * 64; i += 256) {
        int u = i >> 6, j = i & 63;
        float w = (u < 64) ? Wscs[u * 64 + j] : Wl2s[(u - 64) * 64 + j];
        Wt[j * WT_STRIDE + u] = w;
    }
    __syncthreads();

    const int lane = tid & 63;
    const int wave = __builtin_amdgcn_readfirstlane(tid >> 6);
    const int nb   = (blockIdx.x * 4 + wave) * 8;
    if (nb >= Nn) return;
    if (*flag) final_s_body<true >(agg_s, ns, cosb, sinb, attr, out, Nn, Wt, lane, nb);
    else       final_s_body<false>(agg_s, ns, cosb, sinb, attr, out, Nn, Wt, lane, nb);
}

template<bool BF>
__device__ __forceinline__ void final_v_body(
    const float* __restrict__ aggv, const void* __restrict__ nv,
    const float* __restrict__ cosb, const float* __restrict__ sinb,
    const void* __restrict__ attr, void* __restrict__ out,
    int Nn, const float* Wt, int lane, int ub)
{
    const int vi   = lane & 31;
    const int grp  = lane >> 5;       // two row-groups share Wt addresses
    const int NU   = 3 * Nn;
    float acc_sc[8], acc_l2[8];
    int gidx[8], nn_[8], cc_[8];
    #pragma unroll
    for (int r = 0; r < 8; r++) {
        acc_sc[r] = 0.f; acc_l2[r] = 0.f;
        int g = ub + grp * 8 + r;
        if (g > NU - 1) g = NU - 1;
        gidx[r] = g;
        nn_[r] = (int)((unsigned)g / 3u);
        cc_[r] = g - 3 * nn_[r];
    }
    // sc part: u = 0..31 from nv[n][u][c] (stride 3)
    #pragma unroll 2
    for (int t = 0; t < 8; t++) {
        f32x4 wv = *(const f32x4*)&Wt[vi * WT_STRIDE + 4 * t];
        #pragma unroll
        for (int r = 0; r < 8; r++) {
            size_t b = (size_t)nn_[r] * 96 + (size_t)(4 * t) * 3 + cc_[r];
            float x0 = ldf<BF>(nv, b);
            float x1 = ldf<BF>(nv, b + 3);
            float x2 = ldf<BF>(nv, b + 6);
            float x3 = ldf<BF>(nv, b + 9);
            acc_sc[r] = fmaf(x0, wv[0], acc_sc[r]);
            acc_sc[r] = fmaf(x1, wv[1], acc_sc[r]);
            acc_sc[r] = fmaf(x2, wv[2], acc_sc[r]);
            acc_sc[r] = fmaf(x3, wv[3], acc_sc[r]);
        }
    }
    // l2 part: u = 0..127 from c-major aggv rows (contiguous)
    #pragma unroll 2
    for (int t = 0; t < 32; t++) {
        f32x4 wv = *(const f32x4*)&Wt[vi * WT_STRIDE + 32 + 4 * t];
        #pragma unroll
        for (int r = 0; r < 8; r++) {
            f32x4 x = *(const f32x4*)(aggv + (size_t)gidx[r] * 128 + 4 * t);
            acc_l2[r] = fmaf(x[0], wv[0], acc_l2[r]);
            acc_l2[r] = fmaf(x[1], wv[1], acc_l2[r]);
            acc_l2[r] = fmaf(x[2], wv[2], acc_l2[r]);
            acc_l2[r] = fmaf(x[3], wv[3], acc_l2[r]);
        }
    }
    #pragma unroll
    for (int r = 0; r < 8; r++) {
        int g = ub + grp * 8 + r;
        if (g < NU) {
            int n = nn_[r], c = cc_[r];
            float cv = cosb[n], sv = sinb[n];
            float at = ldf<BF>(attr, n);
            stf<BF>(out, (size_t)n * 160 + 64 + vi * 3 + c,
                    at * (cv * acc_sc[r] + sv * acc_l2[r]));
        }
    }
}

__global__ __launch_bounds__(256) void k_final_v(
    const float* __restrict__ aggv, const void* __restrict__ nv,
    const float* __restrict__ Wscv, const float* __restrict__ Wl2v,
    const float* __restrict__ cosb, const float* __restrict__ sinb,
    const void* __restrict__ attr, void* __restrict__ out,
    int Nn, const int* __restrict__ flag)
{
    __shared__ float Wt[32 * WT_STRIDE];   // 20992 B
    const int tid = threadIdx.x;
    // Wt[j][u]: u<32 -> Wscv[u][j]; u>=32 -> Wl2v[u-32][j]
    for (int i = tid; i < 160 * 32; i += 256) {
        int u = i >> 5, j = i & 31;
        float w = (u < 32) ? Wscv[u * 32 + j] : Wl2v[(u - 32) * 32 + j];
        Wt[j * WT_STRIDE + u] = w;
    }
    __syncthreads();

    const int lane = tid & 63;
    const int wave = __builtin_amdgcn_readfirstlane(tid >> 6);
    const int ub   = (blockIdx.x * 4 + wave) * 16;
    if (ub >= 3 * Nn) return;
    if (*flag) final_v_body<true >(aggv, nv, cosb, sinb, attr, out, Nn, Wt, lane, ub);
    else       final_v_body<false>(aggv, nv, cosb, sinb, attr, out, Nn, Wt, lane, ub);
}

// ---------------- fallback fused edge kernel (round-8, verbatim) -----------
#define ES_STRIDE 40
#define H_STRIDE 136
#define WL_STRIDE 225

__global__ __launch_bounds__(256) void k_edge_mfma(
    const void* __restrict__ escal, const void* __restrict__ eattr,
    const void* __restrict__ attr,
    const int* __restrict__ esrc,
    const int* __restrict__ row_start, const int* __restrict__ perm,
    const unsigned short* __restrict__ w1frag, const unsigned short* __restrict__ w2frag,
    const float* __restrict__ Wl3,
    const float* __restrict__ f_s, const float* __restrict__ f_v,
    float* __restrict__ agg_s, float* __restrict__ agg_v,
    float* __restrict__ cosb, float* __restrict__ sinb,
    int Nn, const int* __restrict__ flag)
{
    __shared__ __align__(16) unsigned short es_lds[64 * ES_STRIDE];
    __shared__ __align__(16) unsigned short h_lds[64 * H_STRIDE];
    __shared__ __align__(16) unsigned short w_lds[64 * WL_STRIDE];
    __shared__ float y_lds[64][4];
    __shared__ int   src_lds[64];

    const int tid  = threadIdx.x;
    const int lane = tid & 63;
    const int wave = tid >> 6;
    const int nl   = lane & 15;
    const int quad = lane >> 4;
    const int gbase = blockIdx.x * EG;
    const bool isbf = (*flag != 0);

    for (int i = tid; i < 64 * 22; i += 256) {
        int row = i / 22, k = 10 + (i - row * 22);
        es_lds[row * ES_STRIDE + k] = 0;
    }
    for (int i = tid; i < 64 * 16; i += 256) {
        int row = i >> 4, k = 112 + (i & 15);
        h_lds[row * H_STRIDE + k] = 0;
    }

    const int lane2 = lane & 31;
    const int u0 = lane / 3,  c0 = lane - 3 * u0;
    const int pB = 64 + lane;
    const int uB = pB / 3,    cB = pB - 3 * uB;
    const int p2 = 128 + lane;
    const int u2 = p2 / 3,    c2 = p2 - 3 * u2;
    const int pH = 64 + lane2;
    const int uH = pH / 3,    cH = pH - 3 * uH;
    const bool half = (lane < 32);

    const int node = gbase + wave;
    const int dlo = (node < Nn) ? row_start[node] : 0;
    const int dhi = (node < Nn) ? row_start[node + 1] : 0;

    float acc[9];
    #pragma unroll
    for (int s = 0; s < 9; s++) acc[s] = 0.f;

    const int gend    = (gbase + EG < Nn) ? (gbase + EG) : Nn;
    const int e_start = row_start[gbase];
    const int e_end   = row_start[gend];

    for (int tb = e_start; tb < e_end; tb += 64) {
        const int tcnt = (e_end - tb < 64) ? (e_end - tb) : 64;
        __syncthreads();

        {
            int i = tid & 63, part = tid >> 6;
            if (i < tcnt && part < 2) {
                int e = perm[tb + i];
                if (part == 0) {
                    unsigned int* dstp = (unsigned int*)&es_lds[i * ES_STRIDE];
                    if (isbf) {
                        const unsigned int* srcp =
                            (const unsigned int*)((const unsigned short*)escal + (size_t)e * NBASIS);
                        #pragma unroll
                        for (int t2 = 0; t2 < 5; t2++) dstp[t2] = srcp[t2];
                    } else {
                        const float* srcp = (const float*)escal + (size_t)e * NBASIS;
                        #pragma unroll
                        for (int t2 = 0; t2 < 5; t2++) {
                            unsigned int lo = f2bf(srcp[2 * t2]);
                            unsigned int hi = f2bf(srcp[2 * t2 + 1]);
                            dstp[t2] = lo | (hi << 16);
                        }
                    }
                } else {
                    src_lds[i] = esrc[e];
                    if (isbf) {
                        const unsigned short* ap = (const unsigned short*)eattr + (size_t)e * 4;
                        #pragma unroll
                        for (int t2 = 0; t2 < 4; t2++) y_lds[i][t2] = bf2f(ap[t2]);
                    } else {
                        const float* ap = (const float*)eattr + (size_t)e * 4;
                        #pragma unroll
                        for (int t2 = 0; t2 < 4; t2++) y_lds[i][t2] = ap[t2];
                    }
                }
            }
        }
        __syncthreads();

        {
            short8 a = *(const short8*)&es_lds[(16 * wave + nl) * ES_STRIDE + quad * 8];
            f32x4 hacc[7];
            #pragma unroll
            for (int t = 0; t < 7; t++) {
                short8 b = *(const short8*)&w1frag[(16 * t + nl) * 32 + quad * 8];
                hacc[t] = __builtin_amdgcn_mfma_f32_16x16x32_bf16(
                    a, b, (f32x4){0.f, 0.f, 0.f, 0.f}, 0, 0, 0);
            }
            #pragma unroll
            for (int t = 0; t < 7; t++) {
                #pragma unroll
                for (int r = 0; r < 4; r++)
                    h_lds[(16 * wave + quad * 4 + r) * H_STRIDE + 16 * t + nl] =
                        f2bf(fast_silu(hacc[t][r]));
            }
        }
        __syncthreads();

        #pragma unroll 2
        for (int t = 0; t < 14; t++) {
            f32x4 c = {0.f, 0.f, 0.f, 0.f};
            #pragma unroll
            for (int q = 0; q < 4; q++) {
                short8 a = *(const short8*)&h_lds[(16 * wave + nl) * H_STRIDE + q * 32 + quad * 8];
                short8 b = *(const short8*)&w2frag[((q * 224) + 16 * t + nl) * 32 + quad * 8];
                c = __builtin_amdgcn_mfma_f32_16x16x32_bf16(a, b, c, 0, 0, 0);
            }
            #pragma unroll
            for (int r = 0; r < 4; r++)
                w_lds[(16 * wave + quad * 4 + r) * WL_STRIDE + 16 * t + nl] = f2bf(c[r]);
        }
        __syncthreads();

        {
            int lo = dlo > tb ? dlo : tb;
            int hi = dhi < tb + tcnt ? dhi : tb + tcnt;
            for (int idx = lo; idx < hi; idx++) {
                const int i = idx - tb;
                const int srcn = src_lds[i];
                const float y0  = y_lds[i][0];
                const float y1x = y_lds[i][1];
                const float y1y = y_lds[i][2];
                const float y1z = y_lds[i][3];
                const float* fsr = f_s + (size_t)srcn * 64;
                const float* fvr = f_v + (size_t)srcn * 96;
                const unsigned short* wrow = &w_lds[i * WL_STRIDE];

                float fs_l  = fsr[lane];
                float fs_u0 = fsr[u0];
                float fs_uB = fsr[uB];
                float fs_u2 = fsr[u2];
                float fvA0 = fvr[lane2 * 3], fvA1 = fvr[lane2 * 3 + 1], fvA2 = fvr[lane2 * 3 + 2];
                float fvB0 = fvr[u0 * 3],    fvB1 = fvr[u0 * 3 + 1],    fvB2 = fvr[u0 * 3 + 2];
                float fvH0 = fvr[uH * 3],    fvH1 = fvr[uH * 3 + 1],    fvH2 = fvr[uH * 3 + 2];

                float y1c0 = (c0 == 0) ? y1x : (c0 == 1) ? y1y : y1z;
                float y1cB = (cB == 0) ? y1x : (cB == 1) ? y1y : y1z;
                float y1c2 = (c2 == 0) ? y1x : (c2 == 1) ? y1y : y1z;

                float w_s0 = bf2f(wrow[lane]);
                float w_s1 = bf2f(wrow[160 + lane2]);
                float w_s2 = bf2f(wrow[64 + u0]);
                float w_s3 = bf2f(wrow[64 + uB]);
                float w_s4 = bf2f(wrow[64 + u2]);
                float w_s5 = bf2f(wrow[128 + u0]);
                float w_s6 = bf2f(wrow[128 + uH]);
                float w_s7 = bf2f(wrow[192 + u0]);
                float w_s8 = bf2f(wrow[192 + uH]);

                const float k14 = 0.25f;
                const float k13 = 0.25f * 0.57735026918962576451f;
                const float k12 = 0.25f * 0.70710678118654752440f;

                acc[0] = fmaf(w_s0 * fs_l, y0 * k14, acc[0]);
                {
                    float dot = fvA0 * y1x + fvA1 * y1y + fvA2 * y1z;
                    acc[1] = fmaf(w_s1 * dot, k13, acc[1]);
                }
                acc[2] = fmaf(w_s2 * fs_u0, k14 * y1c0, acc[2]);
                acc[3] = fmaf(w_s3 * fs_uB, k14 * y1cB, acc[3]);
                acc[4] = fmaf(w_s4 * fs_u2, k14 * y1c2, acc[4]);
                {
                    float e5 = (c0 == 0) ? fvB0 : (c0 == 1) ? fvB1 : fvB2;
                    float e6 = (cH == 0) ? fvH0 : (cH == 1) ? fvH1 : fvH2;
                    acc[5] = fmaf(w_s5 * e5, k14 * y0, acc[5]);
                    acc[6] = fmaf(w_s6 * e6, k14 * y0, acc[6]);
                }
                {
                    float cr7 = (c0 == 0) ? (fvB1 * y1z - fvB2 * y1y)
                              : (c0 == 1) ? (fvB2 * y1x - fvB0 * y1z)
                                          : (fvB0 * y1y - fvB1 * y1x);
                    float cr8 = (cH == 0) ? (fvH1 * y1z - fvH2 * y1y)
                              : (cH == 1) ? (fvH2 * y1x - fvH0 * y1z)
                                          : (fvH0 * y1y - fvH1 * y1x);
                    acc[7] = fmaf(w_s7 * cr7, k12, acc[7]);
                    acc[8] = fmaf(w_s8 * cr8, k12, acc[8]);
                }
            }
        }
    }

    if (node < Nn) {
        float* as = agg_s + (size_t)node * MIDS;
        float* av = agg_v + (size_t)node * (MIDV * 3);
        as[lane] = acc[0];
        if (half) as[64 + lane] = acc[1];
        av[lane]       = acc[2];
        av[64 + lane]  = acc[3];
        av[128 + lane] = acc[4];
        av[192 + lane] = acc[5];
        if (half) av[256 + lane] = acc[6];
        av[288 + lane] = acc[7];
        if (half) av[352 + lane] = acc[8];

        float avv = acc[0] * Wl3[lane];
        if (half) avv = fmaf(acc[1], Wl3[64 + lane], avv);
        #pragma unroll
        for (int d = 1; d < 64; d <<= 1) avv += __shfl_xor(avv, d);
        if (lane == 0) {
            float at = isbf ? ldf<true>(attr, node) : ldf<false>(attr, node);
            float a = 0.1f * avv * at;
            cosb[node] = __cosf(a);
            sinb[node] = __sinf(a);
        }
    }
}

// ---------------- k_final (fallback path only, u-major agg_v) --------------
template<bool BF>
__device__ __forceinline__ void final_body(
    const void* __restrict__ ns, const void* __restrict__ nv,
    const void* __restrict__ attr,
    const float* __restrict__ Wscs, const float* __restrict__ Wscv,
    const float* __restrict__ Wl2s, const float* __restrict__ Wl2v,
    const float* __restrict__ agg_s, const float* __restrict__ agg_v,
    const float* __restrict__ cosb, const float* __restrict__ sinb,
    void* __restrict__ out, int Nn)
{
    int i = blockIdx.x * 256 + threadIdx.x;
    int stotal = Nn * MUL0;
    if (i < stotal) {
        int n = i >> 6, j = i & 63;
        const float* ar = agg_s + (size_t)n * MIDS;
        float a1 = 0.f, a2 = 0.f;
        #pragma unroll
        for (int u = 0; u < MUL0; u++)
            a1 = fmaf(ldf<BF>(ns, (size_t)n * MUL0 + u), Wscs[u * MUL0 + j], a1);
        #pragma unroll
        for (int u = 0; u < MIDS; u++) a2 = fmaf(ar[u], Wl2s[u * MUL0 + j], a2);
        float o = ldf<BF>(attr, n) * (cosb[n] * a1 + sinb[n] * a2);
        stf<BF>(out, (size_t)n * 160 + j, o);
    } else {
        int m = i - stotal;
        if (m >= Nn * 96) return;
        int n = m / 96; int idx = m - n * 96;
        int vi = idx / 3; int c = idx - vi * 3;
        const float* ar = agg_v + (size_t)n * (MIDV * 3);
        float a1 = 0.f, a2 = 0.f;
        #pragma unroll
        for (int u = 0; u < MUL1; u++)
            a1 = fmaf(ldf<BF>(nv, (size_t)n * 96 + u * 3 + c), Wscv[u * MUL1 + vi], a1);
        #pragma unroll
        for (int u = 0; u < MIDV; u++) a2 = fmaf(ar[u * 3 + c], Wl2v[u * MUL1 + vi], a2);
        float o = ldf<BF>(attr, n) * (cosb[n] * a1 + sinb[n] * a2);
        stf<BF>(out, (size_t)n * 160 + 64 + idx, o);
    }
}
__global__ __launch_bounds__(256) void k_final(
    const void* ns, const void* nv, const void* attr,
    const float* Wscs, const float* Wscv,
    const float* Wl2s, const float* Wl2v,
    const float* agg_s, const float* agg_v,
    const float* cosb, const float* sinb,
    void* out, int Nn, const int* flag)
{
    if (*flag) final_body<true >(ns, nv, attr, Wscs, Wscv, Wl2s, Wl2v, agg_s, agg_v, cosb, sinb, out, Nn);
    else       final_body<false>(ns, nv, attr, Wscs, Wscv, Wl2s, Wl2v, agg_s, agg_v, cosb, sinb, out, Nn);
}

// ---------------- launch ----------------
extern "C" void kernel_launch(void* const* d_in, const int* in_sizes, int n_in,
                              void* d_out, int out_size, void* d_ws, size_t ws_size,
                              hipStream_t stream)
{
    const void* ns    = d_in[0];
    const void* nv    = d_in[1];
    const void* attr  = d_in[2];
    const int*  esrc  = (const int*)d_in[3];
    const int*  edst  = (const int*)d_in[4];
    const void* eattr = d_in[5];
    const void* escal = d_in[6];

    const int Nn   = in_sizes[2];
    const int Ecnt = in_sizes[3];

    float* ws = (float*)d_ws;
    int* flag = (int*)(ws + OFF_FLAG);
    unsigned short* w1frag = (unsigned short*)(ws + OFF_W1FRAG);
    unsigned short* w2frag = (unsigned short*)(ws + OFF_W2FRAG);

    size_t o = OFF_DYN;
    const size_t OFF_FS   = o; o += (size_t)Nn * 64;
    const size_t OFF_FV   = o; o += (size_t)Nn * 96;
    const size_t OFF_AGGS = o; o += (size_t)Nn * 96;    // agg_s (both paths)
    const size_t OFF_AGGV = o; o += (size_t)Nn * 384;   // split: c-major | fallback: u-major
    const size_t OFF_COS  = o; o += Nn;
    const size_t OFF_SIN  = o; o += Nn;
    const size_t OFF_CNT  = o; o += Nn;
    const size_t OFF_ROW  = o; o += Nn + 1;
    const size_t OFF_CUR  = o; o += Nn;
    const size_t OFF_RPART= o; o += Nn;
    const size_t OFF_BSUM = o; o += 256;
    const size_t OFF_BOFF = o; o += 256;
    const size_t OFF_PERM = o; o += Ecnt;
    const size_t OFF_SRCS = o; o += Ecnt;
    o = (o + 3) & ~(size_t)3;
    const size_t OFF_Y4   = o; o += (size_t)Ecnt * 4;
    o = (o + 15) & ~(size_t)15;
    const size_t OFF_WBUF = o;
    const int tiles = (Ecnt + 63) / 64;
    o += (size_t)tiles * 64 * 112;   // 224 ushorts = 112 floats per row
    const size_t need_bytes = o * sizeof(float);

    int* cnt       = (int*)(ws + OFF_CNT);
    int* row_start = (int*)(ws + OFF_ROW);
    int* cur       = (int*)(ws + OFF_CUR);
    int* row_part  = (int*)(ws + OFF_RPART);
    int* blk_sum   = (int*)(ws + OFF_BSUM);
    int* blk_off   = (int*)(ws + OFF_BOFF);
    int* perm      = (int*)(ws + OFF_PERM);
    int* srcs      = (int*)(ws + OFF_SRCS);
    float* y4      = ws + OFF_Y4;
    unsigned short* wbuf = (unsigned short*)(ws + OFF_WBUF);

    const int NB = (Nn + 255) / 256;
    const bool split = (ws_size >= need_bytes) && (NB <= 256);

    // prep: probe + convert + frag build + cnt zero
    const int prep_work = OFF_WEND + W1FRAG_N + W2FRAG_N + Nn;
    k_prep<<<(prep_work + 255) / 256, 256, 0, stream>>>(
        attr,
        d_in[7], d_in[8], d_in[9], d_in[10], d_in[11], d_in[12],
        d_in[13], d_in[14], d_in[15],
        ws, w1frag, w2frag, cnt, flag, Nn);

    // fused node precompute: s-blocks and v-blocks co-resident
    {
        const int gridS = (Nn + 31) / 32;
        const int gridV = (3 * Nn + 63) / 64;
        k_pre<<<gridS + gridV, 256, 0, stream>>>(
            ns, nv, attr, ws + OFF_WL1S, ws + OFF_WL1V,
            ws + OFF_FS, ws + OFF_FV, Nn, gridS);
    }

    k_hist<<<(Ecnt + 255) / 256, 256, 0, stream>>>(edst, cnt, Ecnt);

    if (split) {
        k_scan_blk<<<NB, 256, 0, stream>>>(cnt, row_part, blk_sum, Nn);
        k_scan_top<<<1, 256, 0, stream>>>(blk_sum, blk_off, row_start, NB, Nn);
        k_rowfix<<<NB, 256, 0, stream>>>(row_part, blk_off, row_start, cur, Nn);
        k_place<<<(Ecnt + 255) / 256, 256, 0, stream>>>(
            edst, esrc, eattr, row_start, cur, perm, srcs, y4, Ecnt, flag, 1);

        k_fc<<<tiles, 256, 0, stream>>>(escal, perm, w1frag, w2frag, wbuf, Ecnt, flag);

        k_agg<<<(Nn + EG - 1) / EG, 256, 0, stream>>>(
            wbuf, srcs, y4, row_start,
            ws + OFF_FS, ws + OFF_FV, ws + OFF_WL3, attr,
            ws + OFF_AGGS, ws + OFF_AGGV, ws + OFF_COS, ws + OFF_SIN,
            Nn, flag);

        k_final_s<<<(Nn + 31) / 32, 256, 0, stream>>>(
            ws + OFF_AGGS, ns, ws + OFF_WSCS, ws + OFF_WL2S,
            ws + OFF_COS, ws + OFF_SIN, attr, (void*)d_out, Nn, flag);
        k_final_v<<<(3 * Nn + 63) / 64, 256, 0, stream>>>(
            ws + OFF_AGGV, nv, ws + OFF_WSCV, ws + OFF_WL2V,
            ws + OFF_COS, ws + OFF_SIN, attr, (void*)d_out, Nn, flag);
    } else {
        k_scan1<<<1, 1024, 0, stream>>>(cnt, row_start, cur, Nn);
        k_place<<<(Ecnt + 255) / 256, 256, 0, stream>>>(
            edst, esrc, eattr, row_start, cur, perm, srcs, y4, Ecnt, flag, 0);
        k_edge_mfma<<<(Nn + EG - 1) / EG, 256, 0, stream>>>(
            escal, eattr, attr, esrc, row_start, perm, w1frag, w2frag,
            ws + OFF_WL3,
            ws + OFF_FS, ws + OFF_FV,
            ws + OFF_AGGS, ws + OFF_AGGV, ws + OFF_COS, ws + OFF_SIN,
            Nn, flag);
        k_final<<<((Nn * 160) + 255) / 256, 256, 0, stream>>>(
            ns, nv, attr,
            ws + OFF_WSCS, ws + OFF_WSCV, ws + OFF_WL2S, ws + OFF_WL2V,
            ws + OFF_AGGS, ws + OFF_AGGV, ws + OFF_COS, ws + OFF_SIN,
            (void*)d_out, Nn, flag);
    }
}

// Round 12
// 463.963 us; speedup vs baseline: 1.0890x; 1.0413x over previous
//
#include <hip/hip_runtime.h>

// ---------------- problem constants ----------------
#define MUL0 64
#define MUL1 32
#define NBASIS 10
#define FCH 100
#define WNUMEL 224   // 2*MUL0 + 3*MUL1
#define MIDS 96      // MUL0 + MUL1
#define MIDV 128     // MUL0 + 2*MUL1
#define EG 4         // dst nodes per workgroup (one per wave)

// weight table offsets inside ws (floats), in d_in[7..15] order
#define OFF_W1   0        // W_fc1  10x100  (1000)
#define OFF_W2   1000     // W_fc2  100x224 (22400)
#define OFF_WSCS 23400    // W_sc_s 64x64   (4096)
#define OFF_WSCV 27496    // W_sc_v 32x32   (1024)
#define OFF_WL1S 28520    // W_l1_s 64x64   (4096)
#define OFF_WL1V 32616    // W_l1_v 32x32   (1024)
#define OFF_WL2S 33640    // W_l2_s 96x64   (6144)
#define OFF_WL2V 39784    // W_l2_v 128x32  (4096)
#define OFF_WL3  43880    // W_l3   96x1    (96)
#define OFF_WEND 43976
#define OFF_FLAG 43980    // dtype flag (int)
#define OFF_W1FRAG 44032  // bf16 frag layout, 3584 ushorts = 1792 floats
#define OFF_W2FRAG 45824  // bf16 frag layout, 28672 ushorts = 14336 floats
#define OFF_DYN  60160    // start of per-node buffers

#define W1FRAG_N (112 * 32)       // 3584
#define W2FRAG_N (4 * 224 * 32)   // 28672

typedef __attribute__((ext_vector_type(8))) short short8;
typedef __attribute__((ext_vector_type(4))) float f32x4;

// ---------------- helpers ----------------
__device__ __forceinline__ float bf2f(unsigned short h) {
    unsigned int u = ((unsigned int)h) << 16;
    float f; __builtin_memcpy(&f, &u, 4); return f;
}
__device__ __forceinline__ unsigned short f2bf(float f) {
    unsigned int u; __builtin_memcpy(&u, &f, 4);
    u += 0x7fffu + ((u >> 16) & 1u);   // round-to-nearest-even
    return (unsigned short)(u >> 16);
}
__device__ __forceinline__ float fast_silu(float x) {
    return x * __builtin_amdgcn_rcpf(1.0f + __expf(-x));
}
template<bool BF>
__device__ __forceinline__ float ldf(const void* p, size_t i) {
    if constexpr (BF) return bf2f(((const unsigned short*)p)[i]);
    else              return ((const float*)p)[i];
}
template<bool BF>
__device__ __forceinline__ void stf(void* p, size_t i, float v) {
    if constexpr (BF) ((unsigned short*)p)[i] = f2bf(v);
    else              ((float*)p)[i] = v;
}
// 4 consecutive elements starting at 4-aligned index i -> f32x4
template<bool BF>
__device__ __forceinline__ f32x4 ld4(const void* p, size_t i) {
    if constexpr (BF) {
        ushort4 h = *(const ushort4*)((const unsigned short*)p + i);
        return (f32x4){bf2f(h.x), bf2f(h.y), bf2f(h.z), bf2f(h.w)};
    } else {
        return *(const f32x4*)((const float*)p + i);
    }
}
__device__ __forceinline__ int wave_incl_scan(int v) {
    int lane = threadIdx.x & 63;
    #pragma unroll
    for (int d = 1; d < 64; d <<= 1) {
        int t = __shfl_up(v, d, 64);
        if (lane >= d) v += t;
    }
    return v;
}

// ---------------- k_prep: probe + convert + frag build + cnt zero ----------
__global__ __launch_bounds__(256) void k_prep(
    const void* __restrict__ attr,
    const void* __restrict__ a0, const void* __restrict__ a1,
    const void* __restrict__ a2, const void* __restrict__ a3,
    const void* __restrict__ a4, const void* __restrict__ a5,
    const void* __restrict__ a6, const void* __restrict__ a7,
    const void* __restrict__ a8,
    float* __restrict__ wsf,
    unsigned short* __restrict__ w1frag, unsigned short* __restrict__ w2frag,
    int* __restrict__ cnt, int* __restrict__ flag, int Nn)
{
    const bool bf = (((const unsigned int*)attr)[0] == 0x3F803F80u);
    int m = blockIdx.x * 256 + threadIdx.x;
    if (m == 0) *flag = bf ? 1 : 0;

    if (m < OFF_WEND) {
        const void* p; int off = m;
        if      (m < OFF_W2)   { p = a0; }
        else if (m < OFF_WSCS) { p = a1; off = m - OFF_W2; }
        else if (m < OFF_WSCV) { p = a2; off = m - OFF_WSCS; }
        else if (m < OFF_WL1S) { p = a3; off = m - OFF_WSCV; }
        else if (m < OFF_WL1V) { p = a4; off = m - OFF_WL1S; }
        else if (m < OFF_WL2S) { p = a5; off = m - OFF_WL1V; }
        else if (m < OFF_WL2V) { p = a6; off = m - OFF_WL2S; }
        else if (m < OFF_WL3)  { p = a7; off = m - OFF_WL2V; }
        else                   { p = a8; off = m - OFF_WL3; }
        wsf[m] = bf ? ldf<true>(p, off) : ldf<false>(p, off);
        return;
    }
    m -= OFF_WEND;
    if (m < W1FRAG_N) {
        int col = m >> 5, k = m & 31;
        float v = 0.f;
        if (col < FCH && k < NBASIS)
            v = bf ? ldf<true>(a0, k * FCH + col) : ldf<false>(a0, k * FCH + col);
        w1frag[m] = f2bf(v);
        return;
    }
    m -= W1FRAG_N;
    if (m < W2FRAG_N) {
        int q = m / (224 * 32); int r = m - q * 224 * 32;
        int n = r >> 5; int kk = r & 31;
        int k = q * 32 + kk;
        float v = 0.f;
        if (k < FCH)
            v = bf ? ldf<true>(a1, k * WNUMEL + n) : ldf<false>(a1, k * WNUMEL + n);
        w2frag[m] = f2bf(v);
        return;
    }
    m -= W2FRAG_N;
    if (m < Nn) cnt[m] = 0;
}

// ---------------- k_pre: fused node precompute (s-blocks + v-blocks) -------
// f_s[n][64] = (ns[n][:] @ W_l1_s) * attr[n]
// f_v[n][u][c] = (sum_k nv[n][k][c] W_l1_v[k][u]) * attr[n]
#define PS_STRIDE 68   // 272 B rows, 17 granules (odd) -> conflict-free b128
#define PV_STRIDE 36   // 144 B rows, 9 granules (odd)

template<bool BF>
__device__ __forceinline__ void pre_s_body(
    const void* __restrict__ ns, const void* __restrict__ attr,
    const float* Wt, float* __restrict__ f_s, int Nn, int lane, int nb)
{
    float acc[8]; int nidx[8];
    #pragma unroll
    for (int r = 0; r < 8; r++) {
        acc[r] = 0.f;
        int n = nb + r; nidx[r] = (n < Nn) ? n : (Nn - 1);
    }
    #pragma unroll 2
    for (int t = 0; t < 16; t++) {
        f32x4 wv = *(const f32x4*)&Wt[lane * PS_STRIDE + 4 * t];
        #pragma unroll
        for (int r = 0; r < 8; r++) {
            f32x4 x = ld4<BF>(ns, (size_t)nidx[r] * 64 + 4 * t);
            acc[r] = fmaf(x[0], wv[0], acc[r]);
            acc[r] = fmaf(x[1], wv[1], acc[r]);
            acc[r] = fmaf(x[2], wv[2], acc[r]);
            acc[r] = fmaf(x[3], wv[3], acc[r]);
        }
    }
    #pragma unroll
    for (int r = 0; r < 8; r++) {
        int n = nb + r;
        if (n < Nn) {
            float at = ldf<BF>(attr, n);
            f_s[(size_t)n * 64 + lane] = acc[r] * at;
        }
    }
}

template<bool BF>
__device__ __forceinline__ void pre_v_body(
    const void* __restrict__ nv, const void* __restrict__ attr,
    const float* Wt, float* __restrict__ f_v, int Nn, int lane, int ub)
{
    const int vi  = lane & 31;
    const int grp = lane >> 5;
    const int NU  = 3 * Nn;
    float acc[8]; int nn_[8], cc_[8];
    #pragma unroll
    for (int r = 0; r < 8; r++) {
        acc[r] = 0.f;
        int g = ub + grp * 8 + r;
        if (g > NU - 1) g = NU - 1;
        nn_[r] = (int)((unsigned)g / 3u);
        cc_[r] = g - 3 * nn_[r];
    }
    #pragma unroll 2
    for (int t = 0; t < 8; t++) {
        f32x4 wv = *(const f32x4*)&Wt[vi * PV_STRIDE + 4 * t];
        #pragma unroll
        for (int r = 0; r < 8; r++) {
            size_t b = (size_t)nn_[r] * 96 + (size_t)(4 * t) * 3 + cc_[r];
            float x0 = ldf<BF>(nv, b);
            float x1 = ldf<BF>(nv, b + 3);
            float x2 = ldf<BF>(nv, b + 6);
            float x3 = ldf<BF>(nv, b + 9);
            acc[r] = fmaf(x0, wv[0], acc[r]);
            acc[r] = fmaf(x1, wv[1], acc[r]);
            acc[r] = fmaf(x2, wv[2], acc[r]);
            acc[r] = fmaf(x3, wv[3], acc[r]);
        }
    }
    #pragma unroll
    for (int r = 0; r < 8; r++) {
        int g = ub + grp * 8 + r;
        if (g < NU) {
            int n = nn_[r], c = cc_[r];
            float at = ldf<BF>(attr, n);
            f_v[(size_t)n * 96 + vi * 3 + c] = acc[r] * at;
        }
    }
}

__global__ __launch_bounds__(256) void k_pre(
    const void* __restrict__ ns, const void* __restrict__ nv,
    const void* __restrict__ attr,
    const float* __restrict__ Wl1s, const float* __restrict__ Wl1v,
    float* __restrict__ f_s, float* __restrict__ f_v, int Nn, int gridS)
{
    __shared__ float Wt[64 * PS_STRIDE];   // 17408 B (v path uses a prefix)
    const int tid = threadIdx.x;
    const bool bf = (((const unsigned int*)attr)[0] == 0x3F803F80u);
    const int lane = tid & 63;
    const int wave = __builtin_amdgcn_readfirstlane(tid >> 6);

    if ((int)blockIdx.x < gridS) {
        for (int i = tid; i < 64 * 64; i += 256) {
            int u = i >> 6, j = i & 63;
            Wt[j * PS_STRIDE + u] = Wl1s[u * 64 + j];
        }
        __syncthreads();
        const int nb = ((int)blockIdx.x * 4 + wave) * 8;
        if (nb >= Nn) return;
        if (bf) pre_s_body<true >(ns, attr, Wt, f_s, Nn, lane, nb);
        else    pre_s_body<false>(ns, attr, Wt, f_s, Nn, lane, nb);
    } else {
        const int vb = (int)blockIdx.x - gridS;
        for (int i = tid; i < 32 * 32; i += 256) {
            int u = i >> 5, vi = i & 31;
            Wt[vi * PV_STRIDE + u] = Wl1v[u * 32 + vi];
        }
        __syncthreads();
        const int ub = (vb * 4 + wave) * 16;
        if (ub >= 3 * Nn) return;
        if (bf) pre_v_body<true >(nv, attr, Wt, f_v, Nn, lane, ub);
        else    pre_v_body<false>(nv, attr, Wt, f_v, Nn, lane, ub);
    }
}

// ---------------- CSR: histogram ----------------
__global__ __launch_bounds__(256) void k_hist(
    const int* __restrict__ edst, int* __restrict__ cnt, int Ecnt)
{
    int e = blockIdx.x * 256 + threadIdx.x;
    if (e < Ecnt) atomicAdd(&cnt[edst[e]], 1);
}

// ---------------- 3-phase parallel scan ----------
__global__ __launch_bounds__(256) void k_scan_blk(
    const int* __restrict__ cnt, int* __restrict__ row_part,
    int* __restrict__ blk_sum, int Nn)
{
    __shared__ int ws4[4];
    int tid = threadIdx.x, lane = tid & 63, wid = tid >> 6;
    int i = blockIdx.x * 256 + tid;
    int v = (i < Nn) ? cnt[i] : 0;
    int incl = wave_incl_scan(v);
    if (lane == 63) ws4[wid] = incl;
    __syncthreads();
    int off = 0;
    #pragma unroll
    for (int w2 = 0; w2 < 4; w2++) off += (w2 < wid) ? ws4[w2] : 0;
    if (i < Nn) row_part[i] = off + incl - v;
    if (tid == 0) blk_sum[blockIdx.x] = ws4[0] + ws4[1] + ws4[2] + ws4[3];
}

__global__ __launch_bounds__(256) void k_scan_top(
    const int* __restrict__ blk_sum, int* __restrict__ blk_off,
    int* __restrict__ row_start, int NB, int Nn)
{
    __shared__ int ws4[4];
    int tid = threadIdx.x, lane = tid & 63, wid = tid >> 6;
    int v = (tid < NB) ? blk_sum[tid] : 0;
    int incl = wave_incl_scan(v);
    if (lane == 63) ws4[wid] = incl;
    __syncthreads();
    int off = 0;
    #pragma unroll
    for (int w2 = 0; w2 < 4; w2++) off += (w2 < wid) ? ws4[w2] : 0;
    if (tid < NB) blk_off[tid] = off + incl - v;
    if (tid == 0) row_start[Nn] = ws4[0] + ws4[1] + ws4[2] + ws4[3];
}

__global__ __launch_bounds__(256) void k_rowfix(
    const int* __restrict__ row_part, const int* __restrict__ blk_off,
    int* __restrict__ row_start, int* __restrict__ cur, int Nn)
{
    int i = blockIdx.x * 256 + threadIdx.x;
    if (i < Nn) { row_start[i] = blk_off[i >> 8] + row_part[i]; cur[i] = 0; }
}

// ---------------- fallback single-wg scan (old path) ----------------
__global__ __launch_bounds__(1024) void k_scan1(
    const int* __restrict__ cnt, int* __restrict__ row_start,
    int* __restrict__ cur, int Nn)
{
    __shared__ int wsum[16];
    __shared__ int s_off, s_tot;
    int tid = threadIdx.x, lane = tid & 63, wid = tid >> 6;
    if (tid == 0) s_off = 0;
    __syncthreads();
    for (int base = 0; base < Nn; base += 1024) {
        int i = base + tid;
        int v = (i < Nn) ? cnt[i] : 0;
        int incl = wave_incl_scan(v);
        if (lane == 63) wsum[wid] = incl;
        __syncthreads();
        if (wid == 0) {
            int wv = (lane < 16) ? wsum[lane] : 0;
            int wincl = wave_incl_scan(wv);
            if (lane < 16) wsum[lane] = wincl - wv;
            if (lane == 15) s_tot = wincl;
        }
        __syncthreads();
        int excl = s_off + wsum[wid] + incl - v;
        if (i < Nn) { row_start[i] = excl; cur[i] = 0; }
        __syncthreads();
        if (tid == 0) s_off += s_tot;
        __syncthreads();
    }
    if (threadIdx.x == 0) row_start[Nn] = s_off;
}

// ---------------- k_place ----------------
__global__ __launch_bounds__(256) void k_place(
    const int* __restrict__ edst, const int* __restrict__ esrc,
    const void* __restrict__ eattr,
    const int* __restrict__ row_start, int* __restrict__ cur,
    int* __restrict__ perm, int* __restrict__ srcs, float* __restrict__ y4,
    int Ecnt, const int* __restrict__ flag, int extras)
{
    int e = blockIdx.x * 256 + threadIdx.x;
    if (e >= Ecnt) return;
    int d = edst[e];
    int pos = row_start[d] + atomicAdd(&cur[d], 1);
    perm[pos] = e;
    if (extras) {
        srcs[pos] = esrc[e];
        float4 yv;
        if (*flag) {
            const unsigned short* ap = (const unsigned short*)eattr + (size_t)e * 4;
            yv = make_float4(bf2f(ap[0]), bf2f(ap[1]), bf2f(ap[2]), bf2f(ap[3]));
        } else {
            const float* ap = (const float*)eattr + (size_t)e * 4;
            yv = make_float4(ap[0], ap[1], ap[2], ap[3]);
        }
        ((float4*)y4)[pos] = yv;
    }
}

// ---------------- k_fc: dense per-edge MLP (MFMA), edge-major wbuf ---------
// FC2 is COLUMN-SPLIT across waves: wave w owns t-tiles (4,4,3,3 split) and
// reuses each B-fragment across the 4 edge-groups (A rows come from the
// block-shared h_lds) -> 4x less w2frag L2 traffic than edge-split.
#define HFC_STRIDE 136   // 272 B rows, 16B-aligned

__global__ __launch_bounds__(256) void k_fc(
    const void* __restrict__ escal, const int* __restrict__ perm,
    const unsigned short* __restrict__ w1frag, const unsigned short* __restrict__ w2frag,
    unsigned short* __restrict__ wbuf, int Ecnt, const int* __restrict__ flag)
{
    __shared__ __align__(16) unsigned short h_lds[64 * HFC_STRIDE]; // 17.4 KB
    const int tid  = threadIdx.x;
    const int lane = tid & 63;
    const int wave = tid >> 6;
    const int nl   = lane & 15;
    const int quad = lane >> 4;
    const int tb   = blockIdx.x * 64;

    // zero h padding cols 112..127
    for (int i = tid; i < 64 * 16; i += 256) {
        int row = i >> 4;
        h_lds[row * HFC_STRIDE + 112 + (i & 15)] = 0;
    }

    // load es A-fragment straight from global (k rows 10..31 are zero)
    int eidx = tb + 16 * wave + nl;
    if (eidx >= Ecnt) eidx = Ecnt - 1;
    const int e = perm[eidx];
    short8 a = {0, 0, 0, 0, 0, 0, 0, 0};
    if (*flag) {
        const unsigned int* p = (const unsigned int*)((const unsigned short*)escal + (size_t)e * NBASIS);
        if (quad == 0) {
            unsigned int d0 = p[0], d1 = p[1], d2 = p[2], d3 = p[3];
            a = (short8){(short)d0, (short)(d0 >> 16), (short)d1, (short)(d1 >> 16),
                         (short)d2, (short)(d2 >> 16), (short)d3, (short)(d3 >> 16)};
        } else if (quad == 1) {
            unsigned int d4 = p[4];
            a = (short8){(short)d4, (short)(d4 >> 16), 0, 0, 0, 0, 0, 0};
        }
    } else {
        const float* p = (const float*)escal + (size_t)e * NBASIS;
        if (quad == 0) {
            a = (short8){(short)f2bf(p[0]), (short)f2bf(p[1]), (short)f2bf(p[2]), (short)f2bf(p[3]),
                         (short)f2bf(p[4]), (short)f2bf(p[5]), (short)f2bf(p[6]), (short)f2bf(p[7])};
        } else if (quad == 1) {
            a = (short8){(short)f2bf(p[8]), (short)f2bf(p[9]), 0, 0, 0, 0, 0, 0};
        }
    }

    // FC1: 7 col-tiles
    {
        f32x4 hacc[7];
        #pragma unroll
        for (int t = 0; t < 7; t++) {
            short8 b = *(const short8*)&w1frag[(16 * t + nl) * 32 + quad * 8];
            hacc[t] = __builtin_amdgcn_mfma_f32_16x16x32_bf16(
                a, b, (f32x4){0.f, 0.f, 0.f, 0.f}, 0, 0, 0);
        }
        #pragma unroll
        for (int t = 0; t < 7; t++) {
            #pragma unroll
            for (int r = 0; r < 4; r++)
                h_lds[(16 * wave + quad * 4 + r) * HFC_STRIDE + 16 * t + nl] =
                    f2bf(fast_silu(hacc[t][r]));
        }
    }
    __syncthreads();

    // FC2 column-split: wave owns t-tiles, B-fragments reused across 4
    // edge-groups. tsta/tend: waves 0,1 -> 4 tiles; waves 2,3 -> 3 tiles.
    {
        const int tsta = (wave < 2) ? wave * 4 : 8 + (wave - 2) * 3;
        const int tend = (wave < 2) ? tsta + 4 : tsta + 3;
        for (int t = tsta; t < tend; t++) {
            short8 b0 = *(const short8*)&w2frag[(0 * 224 + 16 * t + nl) * 32 + quad * 8];
            short8 b1 = *(const short8*)&w2frag[(1 * 224 + 16 * t + nl) * 32 + quad * 8];
            short8 b2 = *(const short8*)&w2frag[(2 * 224 + 16 * t + nl) * 32 + quad * 8];
            short8 b3 = *(const short8*)&w2frag[(3 * 224 + 16 * t + nl) * 32 + quad * 8];
            #pragma unroll
            for (int eg = 0; eg < 4; eg++) {
                const unsigned short* hrow = &h_lds[(16 * eg + nl) * HFC_STRIDE];
                f32x4 c = {0.f, 0.f, 0.f, 0.f};
                c = __builtin_amdgcn_mfma_f32_16x16x32_bf16(
                    *(const short8*)&hrow[0 * 32 + quad * 8], b0, c, 0, 0, 0);
                c = __builtin_amdgcn_mfma_f32_16x16x32_bf16(
                    *(const short8*)&hrow[1 * 32 + quad * 8], b1, c, 0, 0, 0);
                c = __builtin_amdgcn_mfma_f32_16x16x32_bf16(
                    *(const short8*)&hrow[2 * 32 + quad * 8], b2, c, 0, 0, 0);
                c = __builtin_amdgcn_mfma_f32_16x16x32_bf16(
                    *(const short8*)&hrow[3 * 32 + quad * 8], b3, c, 0, 0, 0);
                #pragma unroll
                for (int r = 0; r < 4; r++)
                    wbuf[(size_t)(tb + 16 * eg + quad * 4 + r) * WNUMEL + 16 * t + nl] =
                        f2bf(c[r]);
            }
        }
    }
}

// ---------------- k_agg: one wave per dst; FOUR chains, zero shuffles ------
// agg_s[n][96] coalesced; agg_v stored C-MAJOR: aggv[n*384 + c*128 + u]
// Quarter-split chains, branch-free: invalid indices clamp to dhi-1 and the
// y-vector is zeroed, nullifying every accumulation term (all terms carry a
// y factor on their live path).
__global__ __launch_bounds__(256) void k_agg(
    const unsigned short* __restrict__ wbuf,
    const int* __restrict__ srcs, const float* __restrict__ y4,
    const int* __restrict__ row_start,
    const float* __restrict__ f_s, const float* __restrict__ f_v,
    const float* __restrict__ Wl3, const void* __restrict__ attr,
    float* __restrict__ agg_s, float* __restrict__ aggv,
    float* __restrict__ cosb, float* __restrict__ sinb,
    int Nn, const int* __restrict__ flag)
{
    const int tid  = threadIdx.x;
    const int lane = tid & 63;
    const int wave = tid >> 6;
    const int node = blockIdx.x * EG + wave;
    if (node >= Nn) return;

    const int lane2 = lane & 31;
    const bool hi = (lane >= 32);

    const int dlo = row_start[node];
    const int dhi = row_start[node + 1];
    const int deg = dhi - dlo;
    const int q   = (deg + 3) >> 2;

    const float k14 = 0.25f;
    const float k13 = 0.25f * 0.57735026918962576451f;
    const float k12 = 0.25f * 0.70710678118654752440f;

    float A0[4], A1[4], S0[4], S1[4], S2[4], V0[4], V1[4], V2[4];
    #pragma unroll
    for (int c = 0; c < 4; c++) {
        A0[c] = A1[c] = S0[c] = S1[c] = S2[c] = V0[c] = V1[c] = V2[c] = 0.f;
    }

    for (int j = 0; j < q; j++) {
        #pragma unroll
        for (int c = 0; c < 4; c++) {
            const int idxr = dlo + c * q + j;
            const int idx_ = (idxr < dhi) ? idxr : (dhi - 1);
            const float vm = (idxr < dhi) ? 1.f : 0.f;
            const int srcn = srcs[idx_];
            const float4 y = ((const float4*)y4)[idx_];
            const float y0 = y.x * vm, y1x = y.y * vm, y1y = y.z * vm, y1z = y.w * vm;
            const unsigned short* wrow = wbuf + (size_t)idx_ * WNUMEL;
            const float* fsr = f_s + (size_t)srcn * 64;
            const float* fvr = f_v + (size_t)srcn * 96;
            float fs_l = fsr[lane];
            float v0 = fvr[lane2 * 3 + 0];
            float v1 = fvr[lane2 * 3 + 1];
            float v2 = fvr[lane2 * 3 + 2];
            float w00 = bf2f(wrow[lane]);
            float w01 = bf2f(wrow[64 + lane]);
            float wh  = bf2f(wrow[128 + lane]);
            float wx  = bf2f(wrow[160 + lane]);

            A0[c] = fmaf(w00 * fs_l, y0 * k14, A0[c]);
            float dot_ = v0 * y1x + v1 * y1y + v2 * y1z;
            A1[c] = fmaf(wh * dot_, k13, A1[c]);
            float t1_ = w01 * fs_l * k14;
            S0[c] = fmaf(t1_, y1x, S0[c]);
            S1[c] = fmaf(t1_, y1y, S1[c]);
            S2[c] = fmaf(t1_, y1z, S2[c]);
            float cx_ = v1 * y1z - v2 * y1y;
            float cy_ = v2 * y1x - v0 * y1z;
            float cz_ = v0 * y1y - v1 * y1x;
            float e0_ = hi ? cx_ : v0;
            float e1_ = hi ? cy_ : v1;
            float e2_ = hi ? cz_ : v2;
            float tv_ = hi ? (wx * k12) : (wh * (y0 * k14));
            V0[c] = fmaf(e0_, tv_, V0[c]);
            V1[c] = fmaf(e1_, tv_, V1[c]);
            V2[c] = fmaf(e2_, tv_, V2[c]);
        }
    }

    const float acc0  = (A0[0] + A0[1]) + (A0[2] + A0[3]);
    const float acc1  = (A1[0] + A1[1]) + (A1[2] + A1[3]);
    const float accS0 = (S0[0] + S0[1]) + (S0[2] + S0[3]);
    const float accS1 = (S1[0] + S1[1]) + (S1[2] + S1[3]);
    const float accS2 = (S2[0] + S2[1]) + (S2[2] + S2[3]);
    const float accV0 = (V0[0] + V0[1]) + (V0[2] + V0[3]);
    const float accV1 = (V1[0] + V1[1]) + (V1[2] + V1[3]);
    const float accV2 = (V2[0] + V2[1]) + (V2[2] + V2[3]);

    // writeback: agg_s coalesced; aggv c-major; angle -> cos/sin
    {
        float* as = agg_s + (size_t)node * MIDS;
        float* av = aggv  + (size_t)node * 384;
        as[lane] = acc0;
        if (hi) as[64 + lane2] = acc1;

        av[0 * 128 + lane] = accS0;
        av[1 * 128 + lane] = accS1;
        av[2 * 128 + lane] = accS2;
        const int vrow = hi ? (96 + lane2) : (64 + lane);
        av[0 * 128 + vrow] = accV0;
        av[1 * 128 + vrow] = accV1;
        av[2 * 128 + vrow] = accV2;

        float avv = acc0 * Wl3[lane];
        if (hi) avv = fmaf(acc1, Wl3[64 + lane2], avv);
        #pragma unroll
        for (int d = 1; d < 64; d <<= 1) avv += __shfl_xor(avv, d);
        if (lane == 0) {
            float at = (*flag) ? ldf<true>(attr, node) : ldf<false>(attr, node);
            float aa = 0.1f * avv * at;
            cosb[node] = __cosf(aa);
            sinb[node] = __sinf(aa);
        }
    }
}

// ---------------- k_final_s / k_final_v: LDS-weight register-blocked GEMMs -
// Wt row stride 164 floats = 656 B = 41 (odd) 16B-granules -> within any
// 16-lane phase the granule index == 41*lane mod 8 covers all 8 slots twice
// -> <=2-way LDS access on ds_read_b128 (free, m136).
#define WT_STRIDE 164

template<bool BF>
__device__ __forceinline__ void final_s_body(
    const float* __restrict__ agg_s, const void* __restrict__ ns,
    const float* __restrict__ cosb, const float* __restrict__ sinb,
    const void* __restrict__ attr, void* __restrict__ out,
    int Nn, const float* Wt, int lane, int nb)
{
    float acc_sc[8], acc_l2[8];
    int nidx[8];
    #pragma unroll
    for (int r = 0; r < 8; r++) {
        acc_sc[r] = 0.f; acc_l2[r] = 0.f;
        int n = nb + r; nidx[r] = (n < Nn) ? n : (Nn - 1);
    }
    // sc part: u = 0..63 from ns
    #pragma unroll 2
    for (int t = 0; t < 16; t++) {
        f32x4 wv = *(const f32x4*)&Wt[lane * WT_STRIDE + 4 * t];
        #pragma unroll
        for (int r = 0; r < 8; r++) {
            f32x4 x = ld4<BF>(ns, (size_t)nidx[r] * 64 + 4 * t);
            acc_sc[r] = fmaf(x[0], wv[0], acc_sc[r]);
            acc_sc[r] = fmaf(x[1], wv[1], acc_sc[r]);
            acc_sc[r] = fmaf(x[2], wv[2], acc_sc[r]);
            acc_sc[r] = fmaf(x[3], wv[3], acc_sc[r]);
        }
    }
    // l2 part: u = 0..95 from agg_s
    #pragma unroll 2
    for (int t = 0; t < 24; t++) {
        f32x4 wv = *(const f32x4*)&Wt[lane * WT_STRIDE + 64 + 4 * t];
        #pragma unroll
        for (int r = 0; r < 8; r++) {
            f32x4 x = *(const f32x4*)(agg_s + (size_t)nidx[r] * 96 + 4 * t);
            acc_l2[r] = fmaf(x[0], wv[0], acc_l2[r]);
            acc_l2[r] = fmaf(x[1], wv[1], acc_l2[r]);
            acc_l2[r] = fmaf(x[2], wv[2], acc_l2[r]);
            acc_l2[r] = fmaf(x[3], wv[3], acc_l2[r]);
        }
    }
    #pragma unroll
    for (int r = 0; r < 8; r++) {
        int n = nb + r;
        if (n < Nn) {
            float cv = cosb[n], sv = sinb[n];
            float at = ldf<BF>(attr, n);
            stf<BF>(out, (size_t)n * 160 + lane, at * (cv * acc_sc[r] + sv * acc_l2[r]));
        }
    }
}

__global__ __launch_bounds__(256) void k_final_s(
    const float* __restrict__ agg_s, const void* __restrict__ ns,
    const float* __restrict__ Wscs, const float* __restrict__ Wl2s,
    const float* __restrict__ cosb, const float* __restrict__ sinb,
    const void* __restrict__ attr, void* __restrict__ out,
    int Nn, const int* __restrict__ flag)
{
    __shared__ float Wt[64 * WT_STRIDE];   // 41984 B
    const int tid = threadIdx.x;
    // Wt[j][u]: u<64 -> Wscs[u][j]; u>=64 -> Wl2s[u-64][j]
    for (int i = tid; i < 160 * 64; i += 256) {
        int u = i >> 6, j = i & 63;
        float w = (u < 64) ? Wscs[u * 64 + j] : Wl2s[(u - 64) * 64 + j];
        Wt[j * WT_STRIDE + u] = w;
    }
    __syncthreads();

    const int lane = tid & 63;
    const int wave = __builtin_amdgcn_readfirstlane(tid >> 6);
    const int nb   = (blockIdx.x * 4 + wave) * 8;
    if (nb >= Nn) return;
    if (*flag) final_s_body<true >(agg_s, ns, cosb, sinb, attr, out, Nn, Wt, lane, nb);
    else       final_s_body<false>(agg_s, ns, cosb, sinb, attr, out, Nn, Wt, lane, nb);
}

template<bool BF>
__device__ __forceinline__ void final_v_body(
    const float* __restrict__ aggv, const void* __restrict__ nv,
    const float* __restrict__ cosb, const float* __restrict__ sinb,
    const void* __restrict__ attr, void* __restrict__ out,
    int Nn, const float* Wt, int lane, int ub)
{
    const int vi   = lane & 31;
    const int grp  = lane >> 5;       // two row-groups share Wt addresses
    const int NU   = 3 * Nn;
    float acc_sc[4], acc_l2[4];
    int gidx[4], nn_[4], cc_[4];
    #pragma unroll
    for (int r = 0; r < 4; r++) {
        acc_sc[r] = 0.f; acc_l2[r] = 0.f;
        int g = ub + grp * 4 + r;
        if (g > NU - 1) g = NU - 1;
        gidx[r] = g;
        nn_[r] = (int)((unsigned)g / 3u);
        cc_[r] = g - 3 * nn_[r];
    }
    // sc part: u = 0..31 from nv[n][u][c] (stride 3)
    #pragma unroll 2
    for (int t = 0; t < 8; t++) {
        f32x4 wv = *(const f32x4*)&Wt[vi * WT_STRIDE + 4 * t];
        #pragma unroll
        for (int r = 0; r < 4; r++) {
            size_t b = (size_t)nn_[r] * 96 + (size_t)(4 * t) * 3 + cc_[r];
            float x0 = ldf<BF>(nv, b);
            float x1 = ldf<BF>(nv, b + 3);
            float x2 = ldf<BF>(nv, b + 6);
            float x3 = ldf<BF>(nv, b + 9);
            acc_sc[r] = fmaf(x0, wv[0], acc_sc[r]);
            acc_sc[r] = fmaf(x1, wv[1], acc_sc[r]);
            acc_sc[r] = fmaf(x2, wv[2], acc_sc[r]);
            acc_sc[r] = fmaf(x3, wv[3], acc_sc[r]);
        }
    }
    // l2 part: u = 0..127 from c-major aggv rows (contiguous)
    #pragma unroll 2
    for (int t = 0; t < 32; t++) {
        f32x4 wv = *(const f32x4*)&Wt[vi * WT_STRIDE + 32 + 4 * t];
        #pragma unroll
        for (int r = 0; r < 4; r++) {
            f32x4 x = *(const f32x4*)(aggv + (size_t)gidx[r] * 128 + 4 * t);
            acc_l2[r] = fmaf(x[0], wv[0], acc_l2[r]);
            acc_l2[r] = fmaf(x[1], wv[1], acc_l2[r]);
            acc_l2[r] = fmaf(x[2], wv[2], acc_l2[r]);
            acc_l2[r] = fmaf(x[3], wv[3], acc_l2[r]);
        }
    }
    #pragma unroll
    for (int r = 0; r < 4; r++) {
        int g = ub + grp * 4 + r;
        if (g < NU) {
            int n = nn_[r], c = cc_[r];
            float cv = cosb[n], sv = sinb[n];
            float at = ldf<BF>(attr, n);
            stf<BF>(out, (size_t)n * 160 + 64 + vi * 3 + c,
                    at * (cv * acc_sc[r] + sv * acc_l2[r]));
        }
    }
}

__global__ __launch_bounds__(256) void k_final_v(
    const float* __restrict__ aggv, const void* __restrict__ nv,
    const float* __restrict__ Wscv, const float* __restrict__ Wl2v,
    const float* __restrict__ cosb, const float* __restrict__ sinb,
    const void* __restrict__ attr, void* __restrict__ out,
    int Nn, const int* __restrict__ flag)
{
    __shared__ float Wt[32 * WT_STRIDE];   // 20992 B
    const int tid = threadIdx.x;
    // Wt[j][u]: u<32 -> Wscv[u][j]; u>=32 -> Wl2v[u-32][j]
    for (int i = tid; i < 160 * 32; i += 256) {
        int u = i >> 5, j = i & 31;
        float w = (u < 32) ? Wscv[u * 32 + j] : Wl2v[(u - 32) * 32 + j];
        Wt[j * WT_STRIDE + u] = w;
    }
    __syncthreads();

    const int lane = tid & 63;
    const int wave = __builtin_amdgcn_readfirstlane(tid >> 6);
    const int ub   = (blockIdx.x * 4 + wave) * 8;   // 8 rows/wave (4 per group)
    if (ub >= 3 * Nn) return;
    if (*flag) final_v_body<true >(aggv, nv, cosb, sinb, attr, out, Nn, Wt, lane, ub);
    else       final_v_body<false>(aggv, nv, cosb, sinb, attr, out, Nn, Wt, lane, ub);
}

// ---------------- fallback fused edge kernel (round-8, verbatim) -----------
#define ES_STRIDE 40
#define H_STRIDE 136
#define WL_STRIDE 225

__global__ __launch_bounds__(256) void k_edge_mfma(
    const void* __restrict__ escal, const void* __restrict__ eattr,
    const void* __restrict__ attr,
    const int* __restrict__ esrc,
    const int* __restrict__ row_start, const int* __restrict__ perm,
    const unsigned short* __restrict__ w1frag, const unsigned short* __restrict__ w2frag,
    const float* __restrict__ Wl3,
    const float* __restrict__ f_s, const float* __restrict__ f_v,
    float* __restrict__ agg_s, float* __restrict__ agg_v,
    float* __restrict__ cosb, float* __restrict__ sinb,
    int Nn, const int* __restrict__ flag)
{
    __shared__ __align__(16) unsigned short es_lds[64 * ES_STRIDE];
    __shared__ __align__(16) unsigned short h_lds[64 * H_STRIDE];
    __shared__ __align__(16) unsigned short w_lds[64 * WL_STRIDE];
    __shared__ float y_lds[64][4];
    __shared__ int   src_lds[64];

    const int tid  = threadIdx.x;
    const int lane = tid & 63;
    const int wave = tid >> 6;
    const int nl   = lane & 15;
    const int quad = lane >> 4;
    const int gbase = blockIdx.x * EG;
    const bool isbf = (*flag != 0);

    for (int i = tid; i < 64 * 22; i += 256) {
        int row = i / 22, k = 10 + (i - row * 22);
        es_lds[row * ES_STRIDE + k] = 0;
    }
    for (int i = tid; i < 64 * 16; i += 256) {
        int row = i >> 4, k = 112 + (i & 15);
        h_lds[row * H_STRIDE + k] = 0;
    }

    const int lane2 = lane & 31;
    const int u0 = lane / 3,  c0 = lane - 3 * u0;
    const int pB = 64 + lane;
    const int uB = pB / 3,    cB = pB - 3 * uB;
    const int p2 = 128 + lane;
    const int u2 = p2 / 3,    c2 = p2 - 3 * u2;
    const int pH = 64 + lane2;
    const int uH = pH / 3,    cH = pH - 3 * uH;
    const bool half = (lane < 32);

    const int node = gbase + wave;
    const int dlo = (node < Nn) ? row_start[node] : 0;
    const int dhi = (node < Nn) ? row_start[node + 1] : 0;

    float acc[9];
    #pragma unroll
    for (int s = 0; s < 9; s++) acc[s] = 0.f;

    const int gend    = (gbase + EG < Nn) ? (gbase + EG) : Nn;
    const int e_start = row_start[gbase];
    const int e_end   = row_start[gend];

    for (int tb = e_start; tb < e_end; tb += 64) {
        const int tcnt = (e_end - tb < 64) ? (e_end - tb) : 64;
        __syncthreads();

        {
            int i = tid & 63, part = tid >> 6;
            if (i < tcnt && part < 2) {
                int e = perm[tb + i];
                if (part == 0) {
                    unsigned int* dstp = (unsigned int*)&es_lds[i * ES_STRIDE];
                    if (isbf) {
                        const unsigned int* srcp =
                            (const unsigned int*)((const unsigned short*)escal + (size_t)e * NBASIS);
                        #pragma unroll
                        for (int t2 = 0; t2 < 5; t2++) dstp[t2] = srcp[t2];
                    } else {
                        const float* srcp = (const float*)escal + (size_t)e * NBASIS;
                        #pragma unroll
                        for (int t2 = 0; t2 < 5; t2++) {
                            unsigned int lo = f2bf(srcp[2 * t2]);
                            unsigned int hi = f2bf(srcp[2 * t2 + 1]);
                            dstp[t2] = lo | (hi << 16);
                        }
                    }
                } else {
                    src_lds[i] = esrc[e];
                    if (isbf) {
                        const unsigned short* ap = (const unsigned short*)eattr + (size_t)e * 4;
                        #pragma unroll
                        for (int t2 = 0; t2 < 4; t2++) y_lds[i][t2] = bf2f(ap[t2]);
                    } else {
                        const float* ap = (const float*)eattr + (size_t)e * 4;
                        #pragma unroll
                        for (int t2 = 0; t2 < 4; t2++) y_lds[i][t2] = ap[t2];
                    }
                }
            }
        }
        __syncthreads();

        {
            short8 a = *(const short8*)&es_lds[(16 * wave + nl) * ES_STRIDE + quad * 8];
            f32x4 hacc[7];
            #pragma unroll
            for (int t = 0; t < 7; t++) {
                short8 b = *(const short8*)&w1frag[(16 * t + nl) * 32 + quad * 8];
                hacc[t] = __builtin_amdgcn_mfma_f32_16x16x32_bf16(
                    a, b, (f32x4){0.f, 0.f, 0.f, 0.f}, 0, 0, 0);
            }
            #pragma unroll
            for (int t = 0; t < 7; t++) {
                #pragma unroll
                for (int r = 0; r < 4; r++)
                    h_lds[(16 * wave + quad * 4 + r) * H_STRIDE + 16 * t + nl] =
                        f2bf(fast_silu(hacc[t][r]));
            }
        }
        __syncthreads();

        #pragma unroll 2
        for (int t = 0; t < 14; t++) {
            f32x4 c = {0.f, 0.f, 0.f, 0.f};
            #pragma unroll
            for (int q = 0; q < 4; q++) {
                short8 a = *(const short8*)&h_lds[(16 * wave + nl) * H_STRIDE + q * 32 + quad * 8];
                short8 b = *(const short8*)&w2frag[((q * 224) + 16 * t + nl) * 32 + quad * 8];
                c = __builtin_amdgcn_mfma_f32_16x16x32_bf16(a, b, c, 0, 0, 0);
            }
            #pragma unroll
            for (int r = 0; r < 4; r++)
                w_lds[(16 * wave + quad * 4 + r) * WL_STRIDE + 16 * t + nl] = f2bf(c[r]);
        }
        __syncthreads();

        {
            int lo = dlo > tb ? dlo : tb;
            int hi = dhi < tb + tcnt ? dhi : tb + tcnt;
            for (int idx = lo; idx < hi; idx++) {
                const int i = idx - tb;
                const int srcn = src_lds[i];
                const float y0  = y_lds[i][0];
                const float y1x = y_lds[i][1];
                const float y1y = y_lds[i][2];
                const float y1z = y_lds[i][3];
                const float* fsr = f_s + (size_t)srcn * 64;
                const float* fvr = f_v + (size_t)srcn * 96;
                const unsigned short* wrow = &w_lds[i * WL_STRIDE];

                float fs_l  = fsr[lane];
                float fs_u0 = fsr[u0];
                float fs_uB = fsr[uB];
                float fs_u2 = fsr[u2];
                float fvA0 = fvr[lane2 * 3], fvA1 = fvr[lane2 * 3 + 1], fvA2 = fvr[lane2 * 3 + 2];
                float fvB0 = fvr[u0 * 3],    fvB1 = fvr[u0 * 3 + 1],    fvB2 = fvr[u0 * 3 + 2];
                float fvH0 = fvr[uH * 3],    fvH1 = fvr[uH * 3 + 1],    fvH2 = fvr[uH * 3 + 2];

                float y1c0 = (c0 == 0) ? y1x : (c0 == 1) ? y1y : y1z;
                float y1cB = (cB == 0) ? y1x : (cB == 1) ? y1y : y1z;
                float y1c2 = (c2 == 0) ? y1x : (c2 == 1) ? y1y : y1z;

                float w_s0 = bf2f(wrow[lane]);
                float w_s1 = bf2f(wrow[160 + lane2]);
                float w_s2 = bf2f(wrow[64 + u0]);
                float w_s3 = bf2f(wrow[64 + uB]);
                float w_s4 = bf2f(wrow[64 + u2]);
                float w_s5 = bf2f(wrow[128 + u0]);
                float w_s6 = bf2f(wrow[128 + uH]);
                float w_s7 = bf2f(wrow[192 + u0]);
                float w_s8 = bf2f(wrow[192 + uH]);

                const float k14 = 0.25f;
                const float k13 = 0.25f * 0.57735026918962576451f;
                const float k12 = 0.25f * 0.70710678118654752440f;

                acc[0] = fmaf(w_s0 * fs_l, y0 * k14, acc[0]);
                {
                    float dot = fvA0 * y1x + fvA1 * y1y + fvA2 * y1z;
                    acc[1] = fmaf(w_s1 * dot, k13, acc[1]);
                }
                acc[2] = fmaf(w_s2 * fs_u0, k14 * y1c0, acc[2]);
                acc[3] = fmaf(w_s3 * fs_uB, k14 * y1cB, acc[3]);
                acc[4] = fmaf(w_s4 * fs_u2, k14 * y1c2, acc[4]);
                {
                    float e5 = (c0 == 0) ? fvB0 : (c0 == 1) ? fvB1 : fvB2;
                    float e6 = (cH == 0) ? fvH0 : (cH == 1) ? fvH1 : fvH2;
                    acc[5] = fmaf(w_s5 * e5, k14 * y0, acc[5]);
                    acc[6] = fmaf(w_s6 * e6, k14 * y0, acc[6]);
                }
                {
                    float cr7 = (c0 == 0) ? (fvB1 * y1z - fvB2 * y1y)
                              : (c0 == 1) ? (fvB2 * y1x - fvB0 * y1z)
                                          : (fvB0 * y1y - fvB1 * y1x);
                    float cr8 = (cH == 0) ? (fvH1 * y1z - fvH2 * y1y)
                              : (cH == 1) ? (fvH2 * y1x - fvH0 * y1z)
                                          : (fvH0 * y1y - fvH1 * y1x);
                    acc[7] = fmaf(w_s7 * cr7, k12, acc[7]);
                    acc[8] = fmaf(w_s8 * cr8, k12, acc[8]);
                }
            }
        }
    }

    if (node < Nn) {
        float* as = agg_s + (size_t)node * MIDS;
        float* av = agg_v + (size_t)node * (MIDV * 3);
        as[lane] = acc[0];
        if (half) as[64 + lane] = acc[1];
        av[lane]       = acc[2];
        av[64 + lane]  = acc[3];
        av[128 + lane] = acc[4];
        av[192 + lane] = acc[5];
        if (half) av[256 + lane] = acc[6];
        av[288 + lane] = acc[7];
        if (half) av[352 + lane] = acc[8];

        float avv = acc[0] * Wl3[lane];
        if (half) avv = fmaf(acc[1], Wl3[64 + lane], avv);
        #pragma unroll
        for (int d = 1; d < 64; d <<= 1) avv += __shfl_xor(avv, d);
        if (lane == 0) {
            float at = isbf ? ldf<true>(attr, node) : ldf<false>(attr, node);
            float a = 0.1f * avv * at;
            cosb[node] = __cosf(a);
            sinb[node] = __sinf(a);
        }
    }
}

// ---------------- k_final (fallback path only, u-major agg_v) --------------
template<bool BF>
__device__ __forceinline__ void final_body(
    const void* __restrict__ ns, const void* __restrict__ nv,
    const void* __restrict__ attr,
    const float* __restrict__ Wscs, const float* __restrict__ Wscv,
    const float* __restrict__ Wl2s, const float* __restrict__ Wl2v,
    const float* __restrict__ agg_s, const float* __restrict__ agg_v,
    const float* __restrict__ cosb, const float* __restrict__ sinb,
    void* __restrict__ out, int Nn)
{
    int i = blockIdx.x * 256 + threadIdx.x;
    int stotal = Nn * MUL0;
    if (i < stotal) {
        int n = i >> 6, j = i & 63;
        const float* ar = agg_s + (size_t)n * MIDS;
        float a1 = 0.f, a2 = 0.f;
        #pragma unroll
        for (int u = 0; u < MUL0; u++)
            a1 = fmaf(ldf<BF>(ns, (size_t)n * MUL0 + u), Wscs[u * MUL0 + j], a1);
        #pragma unroll
        for (int u = 0; u < MIDS; u++) a2 = fmaf(ar[u], Wl2s[u * MUL0 + j], a2);
        float o = ldf<BF>(attr, n) * (cosb[n] * a1 + sinb[n] * a2);
        stf<BF>(out, (size_t)n * 160 + j, o);
    } else {
        int m = i - stotal;
        if (m >= Nn * 96) return;
        int n = m / 96; int idx = m - n * 96;
        int vi = idx / 3; int c = idx - vi * 3;
        const float* ar = agg_v + (size_t)n * (MIDV * 3);
        float a1 = 0.f, a2 = 0.f;
        #pragma unroll
        for (int u = 0; u < MUL1; u++)
            a1 = fmaf(ldf<BF>(nv, (size_t)n * 96 + u * 3 + c), Wscv[u * MUL1 + vi], a1);
        #pragma unroll
        for (int u = 0; u < MIDV; u++) a2 = fmaf(ar[u * 3 + c], Wl2v[u * MUL1 + vi], a2);
        float o = ldf<BF>(attr, n) * (cosb[n] * a1 + sinb[n] * a2);
        stf<BF>(out, (size_t)n * 160 + 64 + idx, o);
    }
}
__global__ __launch_bounds__(256) void k_final(
    const void* ns, const void* nv, const void* attr,
    const float* Wscs, const float* Wscv,
    const float* Wl2s, const float* Wl2v,
    const float* agg_s, const float* agg_v,
    const float* cosb, const float* sinb,
    void* out, int Nn, const int* flag)
{
    if (*flag) final_body<true >(ns, nv, attr, Wscs, Wscv, Wl2s, Wl2v, agg_s, agg_v, cosb, sinb, out, Nn);
    else       final_body<false>(ns, nv, attr, Wscs, Wscv, Wl2s, Wl2v, agg_s, agg_v, cosb, sinb, out, Nn);
}

// ---------------- launch ----------------
extern "C" void kernel_launch(void* const* d_in, const int* in_sizes, int n_in,
                              void* d_out, int out_size, void* d_ws, size_t ws_size,
                              hipStream_t stream)
{
    const void* ns    = d_in[0];
    const void* nv    = d_in[1];
    const void* attr  = d_in[2];
    const int*  esrc  = (const int*)d_in[3];
    const int*  edst  = (const int*)d_in[4];
    const void* eattr = d_in[5];
    const void* escal = d_in[6];

    const int Nn   = in_sizes[2];
    const int Ecnt = in_sizes[3];

    float* ws = (float*)d_ws;
    int* flag = (int*)(ws + OFF_FLAG);
    unsigned short* w1frag = (unsigned short*)(ws + OFF_W1FRAG);
    unsigned short* w2frag = (unsigned short*)(ws + OFF_W2FRAG);

    size_t o = OFF_DYN;
    const size_t OFF_FS   = o; o += (size_t)Nn * 64;
    const size_t OFF_FV   = o; o += (size_t)Nn * 96;
    const size_t OFF_AGGS = o; o += (size_t)Nn * 96;    // agg_s (both paths)
    const size_t OFF_AGGV = o; o += (size_t)Nn * 384;   // split: c-major | fallback: u-major
    const size_t OFF_COS  = o; o += Nn;
    const size_t OFF_SIN  = o; o += Nn;
    const size_t OFF_CNT  = o; o += Nn;
    const size_t OFF_ROW  = o; o += Nn + 1;
    const size_t OFF_CUR  = o; o += Nn;
    const size_t OFF_RPART= o; o += Nn;
    const size_t OFF_BSUM = o; o += 256;
    const size_t OFF_BOFF = o; o += 256;
    const size_t OFF_PERM = o; o += Ecnt;
    const size_t OFF_SRCS = o; o += Ecnt;
    o = (o + 3) & ~(size_t)3;
    const size_t OFF_Y4   = o; o += (size_t)Ecnt * 4;
    o = (o + 15) & ~(size_t)15;
    const size_t OFF_WBUF = o;
    const int tiles = (Ecnt + 63) / 64;
    o += (size_t)tiles * 64 * 112;   // 224 ushorts = 112 floats per row
    const size_t need_bytes = o * sizeof(float);

    int* cnt       = (int*)(ws + OFF_CNT);
    int* row_start = (int*)(ws + OFF_ROW);
    int* cur       = (int*)(ws + OFF_CUR);
    int* row_part  = (int*)(ws + OFF_RPART);
    int* blk_sum   = (int*)(ws + OFF_BSUM);
    int* blk_off   = (int*)(ws + OFF_BOFF);
    int* perm      = (int*)(ws + OFF_PERM);
    int* srcs      = (int*)(ws + OFF_SRCS);
    float* y4      = ws + OFF_Y4;
    unsigned short* wbuf = (unsigned short*)(ws + OFF_WBUF);

    const int NB = (Nn + 255) / 256;
    const bool split = (ws_size >= need_bytes) && (NB <= 256);

    // prep: probe + convert + frag build + cnt zero
    const int prep_work = OFF_WEND + W1FRAG_N + W2FRAG_N + Nn;
    k_prep<<<(prep_work + 255) / 256, 256, 0, stream>>>(
        attr,
        d_in[7], d_in[8], d_in[9], d_in[10], d_in[11], d_in[12],
        d_in[13], d_in[14], d_in[15],
        ws, w1frag, w2frag, cnt, flag, Nn);

    // fused node precompute: s-blocks and v-blocks co-resident
    {
        const int gridS = (Nn + 31) / 32;
        const int gridV = (3 * Nn + 63) / 64;
        k_pre<<<gridS + gridV, 256, 0, stream>>>(
            ns, nv, attr, ws + OFF_WL1S, ws + OFF_WL1V,
            ws + OFF_FS, ws + OFF_FV, Nn, gridS);
    }

    k_hist<<<(Ecnt + 255) / 256, 256, 0, stream>>>(edst, cnt, Ecnt);

    if (split) {
        k_scan_blk<<<NB, 256, 0, stream>>>(cnt, row_part, blk_sum, Nn);
        k_scan_top<<<1, 256, 0, stream>>>(blk_sum, blk_off, row_start, NB, Nn);
        k_rowfix<<<NB, 256, 0, stream>>>(row_part, blk_off, row_start, cur, Nn);
        k_place<<<(Ecnt + 255) / 256, 256, 0, stream>>>(
            edst, esrc, eattr, row_start, cur, perm, srcs, y4, Ecnt, flag, 1);

        k_fc<<<tiles, 256, 0, stream>>>(escal, perm, w1frag, w2frag, wbuf, Ecnt, flag);

        k_agg<<<(Nn + EG - 1) / EG, 256, 0, stream>>>(
            wbuf, srcs, y4, row_start,
            ws + OFF_FS, ws + OFF_FV, ws + OFF_WL3, attr,
            ws + OFF_AGGS, ws + OFF_AGGV, ws + OFF_COS, ws + OFF_SIN,
            Nn, flag);

        k_final_s<<<(Nn + 31) / 32, 256, 0, stream>>>(
            ws + OFF_AGGS, ns, ws + OFF_WSCS, ws + OFF_WL2S,
            ws + OFF_COS, ws + OFF_SIN, attr, (void*)d_out, Nn, flag);
        k_final_v<<<(3 * Nn + 31) / 32, 256, 0, stream>>>(
            ws + OFF_AGGV, nv, ws + OFF_WSCV, ws + OFF_WL2V,
            ws + OFF_COS, ws + OFF_SIN, attr, (void*)d_out, Nn, flag);
    } else {
        k_scan1<<<1, 1024, 0, stream>>>(cnt, row_start, cur, Nn);
        k_place<<<(Ecnt + 255) / 256, 256, 0, stream>>>(
            edst, esrc, eattr, row_start, cur, perm, srcs, y4, Ecnt, flag, 0);
        k_edge_mfma<<<(Nn + EG - 1) / EG, 256, 0, stream>>>(
            escal, eattr, attr, esrc, row_start, perm, w1frag, w2frag,
            ws + OFF_WL3,
            ws + OFF_FS, ws + OFF_FV,
            ws + OFF_AGGS, ws + OFF_AGGV, ws + OFF_COS, ws + OFF_SIN,
            Nn, flag);
        k_final<<<((Nn * 160) + 255) / 256, 256, 0, stream>>>(
            ns, nv, attr,
            ws + OFF_WSCS, ws + OFF_WSCV, ws + OFF_WL2S, ws + OFF_WL2V,
            ws + OFF_AGGS, ws + OFF_AGGV, ws + OFF_COS, ws + OFF_SIN,
            (void*)d_out, Nn, flag);
    }
}